// Round 1
// baseline (3610.641 us; speedup 1.0000x reference)
//
#include <hip/hip_runtime.h>
#include <math.h>

#define NH 16
#define NKV 4
#define HD 128
#define SEQ 2048
#define BATCH 2
#define EPSF 1e-6f

// ---------------------------------------------------------------------------
// GEMM NT (fp32): C[M,N] = A[M,K] @ B[N,K]^T   (both row-major, K contiguous)
// 64x64 tile, 256 threads, 4x4 microtile, K-tile 16.
// ---------------------------------------------------------------------------
__global__ __launch_bounds__(256)
void gemm_nt_f32(const float* __restrict__ A, const float* __restrict__ Bm,
                 float* __restrict__ C, int M, int N, int K)
{
    __shared__ float As[16][68];   // [k][m], pad 68 (16B-aligned rows, 2-way max)
    __shared__ float Bs[16][68];   // [k][n]

    const int tid = threadIdx.x;
    const int tx = tid & 15, ty = tid >> 4;
    const int m0 = blockIdx.y * 64, n0 = blockIdx.x * 64;

    const int lrow = tid >> 2;        // 0..63
    const int lk   = (tid & 3) * 4;   // 0,4,8,12
    const float* Ap = A + (size_t)(m0 + lrow) * K + lk;
    const float* Bp = Bm + (size_t)(n0 + lrow) * K + lk;

    float acc[4][4] = {};

    for (int k0 = 0; k0 < K; k0 += 16) {
        float4 av = *(const float4*)(Ap + k0);
        float4 bv = *(const float4*)(Bp + k0);
        __syncthreads();   // protect LDS reuse from previous iteration
        As[lk+0][lrow] = av.x; As[lk+1][lrow] = av.y;
        As[lk+2][lrow] = av.z; As[lk+3][lrow] = av.w;
        Bs[lk+0][lrow] = bv.x; Bs[lk+1][lrow] = bv.y;
        Bs[lk+2][lrow] = bv.z; Bs[lk+3][lrow] = bv.w;
        __syncthreads();

        #pragma unroll
        for (int kk = 0; kk < 16; ++kk) {
            float4 a = *(const float4*)&As[kk][ty * 4];
            float4 b = *(const float4*)&Bs[kk][tx * 4];
            float ar[4] = {a.x, a.y, a.z, a.w};
            float br[4] = {b.x, b.y, b.z, b.w};
            #pragma unroll
            for (int i = 0; i < 4; ++i)
                #pragma unroll
                for (int j = 0; j < 4; ++j)
                    acc[i][j] += ar[i] * br[j];
        }
    }

    #pragma unroll
    for (int i = 0; i < 4; ++i) {
        float4 ov;
        ov.x = acc[i][0]; ov.y = acc[i][1]; ov.z = acc[i][2]; ov.w = acc[i][3];
        *(float4*)&C[(size_t)(m0 + ty * 4 + i) * N + n0 + tx * 4] = ov;
    }
}

// ---------------------------------------------------------------------------
// Fused RMSNorm (over HD=128) + RoPE, in place.
// One wave (64 lanes) per head-vector; lane t handles d=t and d=t+64 (RoPE pair).
// Block = 256 threads = 4 vectors.
// ---------------------------------------------------------------------------
__global__ __launch_bounds__(256)
void norm_rope(float* __restrict__ q, float* __restrict__ k,
               const float* __restrict__ qw, const float* __restrict__ kw)
{
    const int wave = threadIdx.x >> 6;
    const int lane = threadIdx.x & 63;
    const long vec = (long)blockIdx.x * 4 + wave;
    const long NQ = (long)BATCH * SEQ * NH;

    float* base;
    const float* w;
    int s;
    if (vec < NQ) {
        s = (int)((vec / NH) % SEQ);
        base = q + vec * HD;
        w = qw;
    } else {
        long t = vec - NQ;
        s = (int)((t / NKV) % SEQ);
        base = k + t * HD;
        w = kw;
    }

    float x0 = base[lane];
    float x1 = base[lane + 64];
    float ss = x0 * x0 + x1 * x1;
    #pragma unroll
    for (int off = 32; off; off >>= 1) ss += __shfl_xor(ss, off, 64);
    const float r = rsqrtf(ss * (1.0f / HD) + EPSF);
    x0 = x0 * r * w[lane];
    x1 = x1 * r * w[lane + 64];

    // RoPE: inv_freq = 10000^(-lane/64); ang = s * inv_freq
    const float inv_freq = expf(-(float)lane * (logf(10000.0f) / 64.0f));
    const float ang = (float)s * inv_freq;
    const float c = cosf(ang);
    const float sn = sinf(ang);
    base[lane]      = x0 * c - x1 * sn;
    base[lane + 64] = x1 * c + x0 * sn;
}

// ---------------------------------------------------------------------------
// Flash-style causal GQA attention, fp32.
// Block = 256 threads handles (b, h, 64 q-rows). Thread = (row r = tid>>2,
// quarter qd = tid&3). Q row held in registers (interleaved d = qd*4+jj*16).
// Scores: partial dot over own 32 dims, shfl-reduce over the 4 lanes of a row.
// Online softmax fully thread-local afterwards. O accum in registers.
// K/V tiles (32 x 128) staged in LDS. Output written over the q buffer.
// ---------------------------------------------------------------------------
__global__ __launch_bounds__(256)
void flash_attn_f32(const float* q, const float* __restrict__ k,
                    const float* __restrict__ v, float* o)
{
    __shared__ float Ks[32][132];
    __shared__ float Vs[32][132];

    const int tid = threadIdx.x;
    const int bx = blockIdx.x;
    const int qt = bx & 31;           // SEQ/64 = 32 q-tiles
    const int h  = (bx >> 5) & 15;
    const int b  = bx >> 9;
    const int kvh = h >> 2;           // GQA: NH/NKV = 4
    const int q0 = qt * 64;
    const int r  = tid >> 2;
    const int qd = tid & 3;
    const int rg = q0 + r;

    const float scale = 0.08838834764831845f;  // 1/sqrt(128)

    // Q row -> registers, pre-scaled
    float4 qreg[8];
    const float* qrow = q + (((size_t)(b * SEQ + rg) * NH) + h) * HD;
    #pragma unroll
    for (int jj = 0; jj < 8; ++jj) {
        float4 t = *(const float4*)(qrow + qd * 4 + jj * 16);
        qreg[jj].x = t.x * scale; qreg[jj].y = t.y * scale;
        qreg[jj].z = t.z * scale; qreg[jj].w = t.w * scale;
    }

    float4 O[8];
    #pragma unroll
    for (int jj = 0; jj < 8; ++jj) O[jj] = make_float4(0.f, 0.f, 0.f, 0.f);
    float m = -1e30f, l = 0.f;

    const float* kbase = k + ((size_t)b * SEQ * NKV + kvh) * HD;
    const float* vbase = v + ((size_t)b * SEQ * NKV + kvh) * HD;

    const int nkt = (q0 + 64) / 32;   // causal: only tiles with k0 <= q0+63
    for (int kt = 0; kt < nkt; ++kt) {
        const int k0 = kt * 32;
        __syncthreads();
        #pragma unroll
        for (int i = 0; i < 4; ++i) {
            int idx = tid + i * 256;        // 0..1023 float4 units
            int row = idx >> 5;
            int c4  = (idx & 31) * 4;
            size_t goff = (size_t)(k0 + row) * (NKV * HD) + c4;
            *(float4*)&Ks[row][c4] = *(const float4*)(kbase + goff);
            *(float4*)&Vs[row][c4] = *(const float4*)(vbase + goff);
        }
        __syncthreads();

        // scores for all 32 keys of this tile
        float sc[32];
        #pragma unroll
        for (int c = 0; c < 32; ++c) {
            float s = 0.f;
            #pragma unroll
            for (int jj = 0; jj < 8; ++jj) {
                float4 kv = *(const float4*)&Ks[c][qd * 4 + jj * 16];
                s += qreg[jj].x * kv.x + qreg[jj].y * kv.y
                   + qreg[jj].z * kv.z + qreg[jj].w * kv.w;
            }
            s += __shfl_xor(s, 1, 64);
            s += __shfl_xor(s, 2, 64);
            sc[c] = (k0 + c > rg) ? -1e30f : s;
        }

        // online softmax (thread-local; all 4 lanes of a row hold identical state)
        float mn = m;
        #pragma unroll
        for (int c = 0; c < 32; ++c) mn = fmaxf(mn, sc[c]);
        const float alpha = expf(m - mn);
        float ps = 0.f;
        #pragma unroll
        for (int c = 0; c < 32; ++c) { sc[c] = expf(sc[c] - mn); ps += sc[c]; }
        l = l * alpha + ps;
        m = mn;
        #pragma unroll
        for (int jj = 0; jj < 8; ++jj) {
            O[jj].x *= alpha; O[jj].y *= alpha; O[jj].z *= alpha; O[jj].w *= alpha;
        }

        // O += P @ V_tile
        #pragma unroll
        for (int kk = 0; kk < 32; ++kk) {
            const float pv = sc[kk];
            #pragma unroll
            for (int jj = 0; jj < 8; ++jj) {
                float4 vv = *(const float4*)&Vs[kk][qd * 4 + jj * 16];
                O[jj].x += pv * vv.x; O[jj].y += pv * vv.y;
                O[jj].z += pv * vv.z; O[jj].w += pv * vv.w;
            }
        }
    }

    const float inv_l = 1.0f / l;
    float* orow = o + (((size_t)(b * SEQ + rg) * NH) + h) * HD;
    #pragma unroll
    for (int jj = 0; jj < 8; ++jj) {
        float4 t;
        t.x = O[jj].x * inv_l; t.y = O[jj].y * inv_l;
        t.z = O[jj].z * inv_l; t.w = O[jj].w * inv_l;
        *(float4*)(orow + qd * 4 + jj * 16) = t;
    }
}

// ---------------------------------------------------------------------------
extern "C" void kernel_launch(void* const* d_in, const int* in_sizes, int n_in,
                              void* d_out, int out_size, void* d_ws, size_t ws_size,
                              hipStream_t stream)
{
    const float* hs = (const float*)d_in[0];
    // d_in[1] = attention_mask: exactly causal additive -1e9; enforced structurally.
    const float* Wq = (const float*)d_in[2];
    const float* Wk = (const float*)d_in[3];
    const float* Wv = (const float*)d_in[4];
    const float* Wo = (const float*)d_in[5];
    const float* qw = (const float*)d_in[6];
    const float* kw = (const float*)d_in[7];
    float* out = (float*)d_out;

    // workspace layout (fp32): q [B,S,NH,HD] (reused as attn output), k, v
    float* qbuf = (float*)d_ws;
    float* kbuf = qbuf + (size_t)BATCH * SEQ * NH * HD;    // +8388608
    float* vbuf = kbuf + (size_t)BATCH * SEQ * NKV * HD;   // +2097152
    // total ws use: (8388608 + 2*2097152) * 4 = 48 MB

    const int M = BATCH * SEQ;  // 4096
    dim3 blk(256);

    // projections: x @ W^T
    gemm_nt_f32<<<dim3(2048 / 64, M / 64), blk, 0, stream>>>(hs, Wq, qbuf, M, 2048, 2048);
    gemm_nt_f32<<<dim3(512 / 64,  M / 64), blk, 0, stream>>>(hs, Wk, kbuf, M, 512, 2048);
    gemm_nt_f32<<<dim3(512 / 64,  M / 64), blk, 0, stream>>>(hs, Wv, vbuf, M, 512, 2048);

    // fused RMSNorm + RoPE on q and k (in place)
    norm_rope<<<dim3((BATCH * SEQ * (NH + NKV)) / 4), blk, 0, stream>>>(qbuf, kbuf, qw, kw);

    // causal GQA flash attention; writes attn output back over qbuf
    flash_attn_f32<<<dim3(BATCH * NH * (SEQ / 64)), blk, 0, stream>>>(qbuf, kbuf, vbuf, qbuf);

    // output projection: attn @ Wo^T
    gemm_nt_f32<<<dim3(2048 / 64, M / 64), blk, 0, stream>>>(qbuf, Wo, out, M, 2048, 2048);
}

// Round 3
// 1474.760 us; speedup vs baseline: 2.4483x; 2.4483x over previous
//
#include <hip/hip_runtime.h>
#include <math.h>

#define NH 16
#define NKV 4
#define HD 128
#define SEQ 2048
#define BATCH 2
#define EPSF 1e-6f

typedef __attribute__((ext_vector_type(8))) short bf16x8;
typedef __attribute__((ext_vector_type(4))) short short4v;
typedef __attribute__((ext_vector_type(4))) float f32x4;

__device__ __forceinline__ short f2bf(float x) {
    unsigned u = __float_as_uint(x);
    u += 0x7fffu + ((u >> 16) & 1u);      // round-to-nearest-even
    return (short)(u >> 16);
}

// ---------------------------------------------------------------------------
// GEMM NT (fp32): C[M,N] = A[M,K] @ B[N,K]^T
// ---------------------------------------------------------------------------
__global__ __launch_bounds__(256)
void gemm_nt_f32(const float* __restrict__ A, const float* __restrict__ Bm,
                 float* __restrict__ C, int M, int N, int K)
{
    __shared__ float As[16][68];
    __shared__ float Bs[16][68];

    const int tid = threadIdx.x;
    const int tx = tid & 15, ty = tid >> 4;
    const int m0 = blockIdx.y * 64, n0 = blockIdx.x * 64;

    const int lrow = tid >> 2;
    const int lk   = (tid & 3) * 4;
    const float* Ap = A + (size_t)(m0 + lrow) * K + lk;
    const float* Bp = Bm + (size_t)(n0 + lrow) * K + lk;

    float acc[4][4] = {};

    for (int k0 = 0; k0 < K; k0 += 16) {
        float4 av = *(const float4*)(Ap + k0);
        float4 bv = *(const float4*)(Bp + k0);
        __syncthreads();
        As[lk+0][lrow] = av.x; As[lk+1][lrow] = av.y;
        As[lk+2][lrow] = av.z; As[lk+3][lrow] = av.w;
        Bs[lk+0][lrow] = bv.x; Bs[lk+1][lrow] = bv.y;
        Bs[lk+2][lrow] = bv.z; Bs[lk+3][lrow] = bv.w;
        __syncthreads();

        #pragma unroll
        for (int kk = 0; kk < 16; ++kk) {
            float4 a = *(const float4*)&As[kk][ty * 4];
            float4 b = *(const float4*)&Bs[kk][tx * 4];
            float ar[4] = {a.x, a.y, a.z, a.w};
            float br[4] = {b.x, b.y, b.z, b.w};
            #pragma unroll
            for (int i = 0; i < 4; ++i)
                #pragma unroll
                for (int j = 0; j < 4; ++j)
                    acc[i][j] += ar[i] * br[j];
        }
    }

    #pragma unroll
    for (int i = 0; i < 4; ++i) {
        float4 ov;
        ov.x = acc[i][0]; ov.y = acc[i][1]; ov.z = acc[i][2]; ov.w = acc[i][3];
        *(float4*)&C[(size_t)(m0 + ty * 4 + i) * N + n0 + tx * 4] = ov;
    }
}

// ---------------------------------------------------------------------------
// Fused RMSNorm + RoPE, in place (fp32).
// ---------------------------------------------------------------------------
__global__ __launch_bounds__(256)
void norm_rope(float* __restrict__ q, float* __restrict__ k,
               const float* __restrict__ qw, const float* __restrict__ kw)
{
    const int wave = threadIdx.x >> 6;
    const int lane = threadIdx.x & 63;
    const long vec = (long)blockIdx.x * 4 + wave;
    const long NQ = (long)BATCH * SEQ * NH;

    float* base;
    const float* w;
    int s;
    if (vec < NQ) {
        s = (int)((vec / NH) % SEQ);
        base = q + vec * HD;
        w = qw;
    } else {
        long t = vec - NQ;
        s = (int)((t / NKV) % SEQ);
        base = k + t * HD;
        w = kw;
    }

    float x0 = base[lane];
    float x1 = base[lane + 64];
    float ss = x0 * x0 + x1 * x1;
    #pragma unroll
    for (int off = 32; off; off >>= 1) ss += __shfl_xor(ss, off, 64);
    const float r = rsqrtf(ss * (1.0f / HD) + EPSF);
    x0 = x0 * r * w[lane];
    x1 = x1 * r * w[lane + 64];

    const float inv_freq = expf(-(float)lane * (logf(10000.0f) / 64.0f));
    const float ang = (float)s * inv_freq;
    const float c = cosf(ang);
    const float sn = sinf(ang);
    base[lane]      = x0 * c - x1 * sn;
    base[lane + 64] = x1 * c + x0 * sn;
}

// ---------------------------------------------------------------------------
// Cast+transpose V: fp32 [b][s][kvh][d]  ->  bf16 [b][kvh][d][s]
// ---------------------------------------------------------------------------
__global__ __launch_bounds__(256)
void cast_transpose_v(const float* __restrict__ v, short* __restrict__ vT)
{
    __shared__ float T[32][33];
    const int bx = blockIdx.x;          // B*NKV * (HD/32) * (SEQ/32) = 2048
    const int st = bx & 63;             // s-tile
    const int dt = (bx >> 6) & 3;       // d-tile
    const int bk = bx >> 8;             // b*NKV+kvh, 0..7
    const int b = bk >> 2, kvh = bk & 3;
    const int s0 = st * 32, d0 = dt * 32;
    const int tid = threadIdx.x;

    const int rs = tid >> 3;            // 0..31 (s row)
    const int rc = (tid & 7) * 4;       // 0..28 (d col base)
    float4 val = *(const float4*)(v + ((size_t)((b * SEQ) + s0 + rs) * NKV + kvh) * HD + d0 + rc);
    T[rc + 0][rs] = val.x; T[rc + 1][rs] = val.y;
    T[rc + 2][rs] = val.z; T[rc + 3][rs] = val.w;
    __syncthreads();

    const int wd = tid >> 3;            // d row
    const int wsc = (tid & 7) * 4;      // s col base
    short4v ov;
    ov.x = f2bf(T[wd][wsc + 0]); ov.y = f2bf(T[wd][wsc + 1]);
    ov.z = f2bf(T[wd][wsc + 2]); ov.w = f2bf(T[wd][wsc + 3]);
    *(short4v*)(vT + ((size_t)bk * HD + d0 + wd) * SEQ + s0 + wsc) = ov;
}

// ---------------------------------------------------------------------------
// Flash-style causal GQA attention, bf16 MFMA (16x16x32), fp32 accumulate.
// Block = 256 thr = 4 waves; block handles (b,h,64 q rows); wave = 16 q rows.
// K tiles of 32 keys staged fp32->bf16 in LDS; V read from pre-transposed
// bf16 vT. P goes C-layout -> A-layout via per-wave LDS round-trip.
// ---------------------------------------------------------------------------
__global__ __launch_bounds__(256)
void flash_attn_mfma(const float* __restrict__ q, const float* __restrict__ k,
                     const short* __restrict__ vT, float* __restrict__ o)
{
    __shared__ short Ks[32][136];      // [key][d]   pad->2-way (free)
    __shared__ short Vt[128][40];      // [d][key]   16B-aligned rows
    __shared__ short Ps[4][16][40];    // per-wave P tile [qrow][key]

    const int tid = threadIdx.x;
    const int w = tid >> 6;
    const int lane = tid & 63;
    const int quad = lane >> 4;
    const int ln = lane & 15;

    const int bx = blockIdx.x;
    const int qt = 31 - (bx >> 5);     // heaviest q-tiles dispatch first
    const int h = bx & 15;
    const int b = (bx >> 4) & 1;
    const int kvh = h >> 2;
    const int q0 = qt * 64;
    const int r0 = q0 + w * 16;

    // Q -> A-frags (pre-scaled by softmax_scale * log2(e))
    const float sc = 0.08838834764831845f * 1.4426950408889634f;
    bf16x8 qf[4];
    const float* qrow = q + ((size_t)(b * SEQ + r0 + ln) * NH + h) * HD;
    #pragma unroll
    for (int f = 0; f < 4; ++f) {
        const float* p = qrow + f * 32 + quad * 8;
        float4 a = *(const float4*)p;
        float4 bq = *(const float4*)(p + 4);
        qf[f][0] = f2bf(a.x * sc);  qf[f][1] = f2bf(a.y * sc);
        qf[f][2] = f2bf(a.z * sc);  qf[f][3] = f2bf(a.w * sc);
        qf[f][4] = f2bf(bq.x * sc); qf[f][5] = f2bf(bq.y * sc);
        qf[f][6] = f2bf(bq.z * sc); qf[f][7] = f2bf(bq.w * sc);
    }

    f32x4 Oa[8];
    #pragma unroll
    for (int dg = 0; dg < 8; ++dg) Oa[dg] = (f32x4){0.f, 0.f, 0.f, 0.f};
    float mrow[4] = {-1e30f, -1e30f, -1e30f, -1e30f};
    float lrow[4] = {0.f, 0.f, 0.f, 0.f};

    const float* kbase = k + ((size_t)b * SEQ * NKV + kvh) * HD;
    const short* vbase = vT + (size_t)(b * NKV + kvh) * HD * SEQ;

    const int nkt = (q0 + 64) >> 5;
    for (int kt = 0; kt < nkt; ++kt) {
        const int k0 = kt * 32;
        __syncthreads();
        // stage K tile (fp32 -> bf16), coalesced: 32 keys x 32 float4 = 1024 units
        #pragma unroll
        for (int i = 0; i < 4; ++i) {
            int e = tid + i * 256;
            int key = e >> 5;
            int d0 = (e & 31) * 4;
            float4 kv = *(const float4*)(kbase + (size_t)(k0 + key) * (NKV * HD) + d0);
            short4v pk;
            pk.x = f2bf(kv.x); pk.y = f2bf(kv.y); pk.z = f2bf(kv.z); pk.w = f2bf(kv.w);
            *(short4v*)&Ks[key][d0] = pk;
        }
        // stage V^T tile (bf16): 128 d-rows x 8 short4 = 1024 units (i<4 — was the R2 bug)
        #pragma unroll
        for (int i = 0; i < 4; ++i) {
            int e = tid + i * 256;          // 0..1023
            int d = e >> 3;                 // 0..127
            int kg = (e & 7) * 4;           // 0..28
            short4v vv = *(const short4v*)(vbase + (size_t)d * SEQ + k0 + kg);
            *(short4v*)&Vt[d][kg] = vv;
        }
        __syncthreads();

        if (k0 <= r0 + 15) {               // not fully masked for this wave
            // QK^T: D[q=quad*4+reg][key=ln] per 16-key group
            f32x4 s[2];
            #pragma unroll
            for (int g = 0; g < 2; ++g) {
                f32x4 acc = (f32x4){0.f, 0.f, 0.f, 0.f};
                #pragma unroll
                for (int f = 0; f < 4; ++f) {
                    bf16x8 kf = *(const bf16x8*)&Ks[g * 16 + ln][f * 32 + quad * 8];
                    acc = __builtin_amdgcn_mfma_f32_16x16x32_bf16(qf[f], kf, acc, 0, 0, 0);
                }
                s[g] = acc;
            }

            // causal mask (only diagonal-touching tiles need it)
            if (k0 + 31 > r0) {
                #pragma unroll
                for (int g = 0; g < 2; ++g) {
                    const int keyg = k0 + g * 16 + ln;
                    #pragma unroll
                    for (int reg = 0; reg < 4; ++reg) {
                        const int rowg = r0 + quad * 4 + reg;
                        if (keyg > rowg) s[g][reg] = -1e30f;
                    }
                }
            }

            // online softmax (exp2 domain), per row reg
            float alpha4[4];
            #pragma unroll
            for (int reg = 0; reg < 4; ++reg) {
                float mx = fmaxf(s[0][reg], s[1][reg]);
                mx = fmaxf(mx, __shfl_xor(mx, 1, 64));
                mx = fmaxf(mx, __shfl_xor(mx, 2, 64));
                mx = fmaxf(mx, __shfl_xor(mx, 4, 64));
                mx = fmaxf(mx, __shfl_xor(mx, 8, 64));
                const float mnew = fmaxf(mrow[reg], mx);
                const float alpha = exp2f(mrow[reg] - mnew);
                const float p0 = exp2f(s[0][reg] - mnew);
                const float p1 = exp2f(s[1][reg] - mnew);
                float ps = p0 + p1;
                ps += __shfl_xor(ps, 1, 64);
                ps += __shfl_xor(ps, 2, 64);
                ps += __shfl_xor(ps, 4, 64);
                ps += __shfl_xor(ps, 8, 64);
                lrow[reg] = lrow[reg] * alpha + ps;
                mrow[reg] = mnew;
                alpha4[reg] = alpha;
                Ps[w][quad * 4 + reg][ln]      = f2bf(p0);
                Ps[w][quad * 4 + reg][16 + ln] = f2bf(p1);
            }
            #pragma unroll
            for (int dg = 0; dg < 8; ++dg) {
                Oa[dg][0] *= alpha4[0]; Oa[dg][1] *= alpha4[1];
                Oa[dg][2] *= alpha4[2]; Oa[dg][3] *= alpha4[3];
            }

            __asm volatile("s_waitcnt lgkmcnt(0)" ::: "memory");

            // PV: O[q][d] += P[q][key] * Vt[d][key]
            bf16x8 pf = *(const bf16x8*)&Ps[w][ln][quad * 8];
            #pragma unroll
            for (int dg = 0; dg < 8; ++dg) {
                bf16x8 vf = *(const bf16x8*)&Vt[dg * 16 + ln][quad * 8];
                Oa[dg] = __builtin_amdgcn_mfma_f32_16x16x32_bf16(pf, vf, Oa[dg], 0, 0, 0);
            }
        }
    }

    // epilogue
    #pragma unroll
    for (int reg = 0; reg < 4; ++reg) {
        const float inv = 1.0f / lrow[reg];
        const int row = r0 + quad * 4 + reg;
        float* orow = o + ((size_t)(b * SEQ + row) * NH + h) * HD;
        #pragma unroll
        for (int dg = 0; dg < 8; ++dg)
            orow[dg * 16 + ln] = Oa[dg][reg] * inv;
    }
}

// ---------------------------------------------------------------------------
extern "C" void kernel_launch(void* const* d_in, const int* in_sizes, int n_in,
                              void* d_out, int out_size, void* d_ws, size_t ws_size,
                              hipStream_t stream)
{
    const float* hs = (const float*)d_in[0];
    const float* Wq = (const float*)d_in[2];
    const float* Wk = (const float*)d_in[3];
    const float* Wv = (const float*)d_in[4];
    const float* Wo = (const float*)d_in[5];
    const float* qw = (const float*)d_in[6];
    const float* kw = (const float*)d_in[7];
    float* out = (float*)d_out;

    float* qbuf = (float*)d_ws;
    float* kbuf = qbuf + (size_t)BATCH * SEQ * NH * HD;
    float* vbuf = kbuf + (size_t)BATCH * SEQ * NKV * HD;
    // vT (bf16, 4 MB) lives in d_out, which is untouched until the final GEMM
    short* vT = (short*)d_out;

    const int M = BATCH * SEQ;
    dim3 blk(256);

    gemm_nt_f32<<<dim3(2048 / 64, M / 64), blk, 0, stream>>>(hs, Wq, qbuf, M, 2048, 2048);
    gemm_nt_f32<<<dim3(512 / 64,  M / 64), blk, 0, stream>>>(hs, Wk, kbuf, M, 512, 2048);
    gemm_nt_f32<<<dim3(512 / 64,  M / 64), blk, 0, stream>>>(hs, Wv, vbuf, M, 512, 2048);

    norm_rope<<<dim3((BATCH * SEQ * (NH + NKV)) / 4), blk, 0, stream>>>(qbuf, kbuf, qw, kw);

    cast_transpose_v<<<dim3(2048), blk, 0, stream>>>(vbuf, vT);

    flash_attn_mfma<<<dim3(BATCH * NH * (SEQ / 64)), blk, 0, stream>>>(qbuf, kbuf, vT, qbuf);

    gemm_nt_f32<<<dim3(2048 / 64, M / 64), blk, 0, stream>>>(qbuf, Wo, out, M, 2048, 2048);
}

// Round 4
// 419.999 us; speedup vs baseline: 8.5968x; 3.5113x over previous
//
#include <hip/hip_runtime.h>
#include <math.h>

#define NH 16
#define NKV 4
#define HD 128
#define SEQ 2048
#define BATCH 2
#define EPSF 1e-6f
#define QKV 3072      // fused projection width: 2048 q | 512 k | 512 v

typedef __attribute__((ext_vector_type(8))) short bf16x8;
typedef __attribute__((ext_vector_type(4))) short short4v;
typedef __attribute__((ext_vector_type(4))) float f32x4;

__device__ __forceinline__ short f2bf(float x) {
    unsigned u = __float_as_uint(x);
    u += 0x7fffu + ((u >> 16) & 1u);      // round-to-nearest-even
    return (short)(u >> 16);
}
__device__ __forceinline__ float bf2f(short x) {
    return __uint_as_float((unsigned)(unsigned short)x << 16);
}

// async global->LDS, 16B per lane; LDS dest = wave-uniform base + lane*16
__device__ __forceinline__ void gll16(const short* g, short* l) {
    __builtin_amdgcn_global_load_lds(
        (const __attribute__((address_space(1))) unsigned*)g,
        (__attribute__((address_space(3))) unsigned*)l, 16, 0, 0);
}

// ---------------------------------------------------------------------------
// fp32 -> bf16 cast, 4 elems/thread
// ---------------------------------------------------------------------------
__global__ __launch_bounds__(256)
void cast_f32_bf16(const float* __restrict__ s, short* __restrict__ d)
{
    const size_t i = ((size_t)blockIdx.x * 256 + threadIdx.x) * 4;
    float4 v = *(const float4*)(s + i);
    short4v o;
    o.x = f2bf(v.x); o.y = f2bf(v.y); o.z = f2bf(v.z); o.w = f2bf(v.w);
    *(short4v*)(d + i) = o;
}

// ---------------------------------------------------------------------------
// bf16 MFMA GEMM NT: C[M,N] = A[M,K] @ B[N,K]^T, fp32 accum.
// m97 structure: 128x128 tile, BK=32, 256 thr (2x2 waves of 64x64),
// global_load_lds width 16, 16 mfma_16x16x32 per wave per K-step.
// ---------------------------------------------------------------------------
template<bool OUT_BF16>
__global__ __launch_bounds__(256)
void gemm_nt_mfma(const short* __restrict__ A, const short* __restrict__ B,
                  void* __restrict__ Cv, int M, int N, int K)
{
    __shared__ short As[128 * 32];    // [row][32k], rows contiguous (no pad: gll)
    __shared__ short Bs[128 * 32];

    const int tid = threadIdx.x;
    const int w = tid >> 6, lane = tid & 63;
    const int quad = lane >> 4, ln = lane & 15;
    const int mw = (w >> 1) * 64, nw = (w & 1) * 64;
    const int m0 = blockIdx.y * 128, n0 = blockIdx.x * 128;

    // staging: lane l of wave w covers tile-row w*16 + l/4, k-col (l%4)*8
    const int srow = w * 16 + (lane >> 2);
    const int scol = (lane & 3) * 8;
    const short* Ag0 = A + (size_t)(m0 + srow) * K + scol;
    const short* Ag1 = Ag0 + (size_t)64 * K;
    const short* Bg0 = B + (size_t)(n0 + srow) * K + scol;
    const short* Bg1 = Bg0 + (size_t)64 * K;
    short* Al0 = &As[(w * 16) * 32];         // wave-uniform LDS bases
    short* Al1 = &As[(w * 16 + 64) * 32];
    short* Bl0 = &Bs[(w * 16) * 32];
    short* Bl1 = &Bs[(w * 16 + 64) * 32];

    f32x4 acc[4][4];
    #pragma unroll
    for (int i = 0; i < 4; ++i)
        #pragma unroll
        for (int j = 0; j < 4; ++j)
            acc[i][j] = (f32x4){0.f, 0.f, 0.f, 0.f};

    for (int k0 = 0; k0 < K; k0 += 32) {
        __syncthreads();
        gll16(Ag0 + k0, Al0);
        gll16(Ag1 + k0, Al1);
        gll16(Bg0 + k0, Bl0);
        gll16(Bg1 + k0, Bl1);
        __syncthreads();   // barrier drains vmcnt -> LDS populated

        bf16x8 af[4], bfr[4];
        #pragma unroll
        for (int i = 0; i < 4; ++i)
            af[i] = *(const bf16x8*)&As[(mw + i * 16 + ln) * 32 + quad * 8];
        #pragma unroll
        for (int j = 0; j < 4; ++j)
            bfr[j] = *(const bf16x8*)&Bs[(nw + j * 16 + ln) * 32 + quad * 8];
        #pragma unroll
        for (int i = 0; i < 4; ++i)
            #pragma unroll
            for (int j = 0; j < 4; ++j)
                acc[i][j] = __builtin_amdgcn_mfma_f32_16x16x32_bf16(
                    af[i], bfr[j], acc[i][j], 0, 0, 0);
    }

    // epilogue: C[row = quad*4+reg (+16i)][col = ln (+16j)]
    #pragma unroll
    for (int i = 0; i < 4; ++i) {
        #pragma unroll
        for (int reg = 0; reg < 4; ++reg) {
            const int row = m0 + mw + i * 16 + quad * 4 + reg;
            const size_t base = (size_t)row * N + n0 + nw;
            #pragma unroll
            for (int j = 0; j < 4; ++j) {
                if (OUT_BF16)
                    ((short*)Cv)[base + j * 16 + ln] = f2bf(acc[i][j][reg]);
                else
                    ((float*)Cv)[base + j * 16 + ln] = acc[i][j][reg];
            }
        }
    }
}

// ---------------------------------------------------------------------------
// Fused RMSNorm + RoPE on bf16 qkv[token][3072], in place (fp32 math).
// One wave per 128-dim head vector; lane t handles d=t and d=t+64.
// ---------------------------------------------------------------------------
__global__ __launch_bounds__(256)
void norm_rope_bf16(short* __restrict__ qkv, const float* __restrict__ qw,
                    const float* __restrict__ kw)
{
    const int wave = threadIdx.x >> 6;
    const int lane = threadIdx.x & 63;
    const long vec = (long)blockIdx.x * 4 + wave;
    const long NQ = (long)BATCH * SEQ * NH;

    short* base;
    const float* w;
    int s;
    if (vec < NQ) {
        const long token = vec / NH;
        const int h = (int)(vec % NH);
        s = (int)(token % SEQ);
        base = qkv + token * QKV + h * HD;
        w = qw;
    } else {
        const long t = vec - NQ;
        const long token = t / NKV;
        const int kvh = (int)(t % NKV);
        s = (int)(token % SEQ);
        base = qkv + token * QKV + 2048 + kvh * HD;
        w = kw;
    }

    float x0 = bf2f(base[lane]);
    float x1 = bf2f(base[lane + 64]);
    float ss = x0 * x0 + x1 * x1;
    #pragma unroll
    for (int off = 32; off; off >>= 1) ss += __shfl_xor(ss, off, 64);
    const float r = rsqrtf(ss * (1.0f / HD) + EPSF);
    x0 = x0 * r * w[lane];
    x1 = x1 * r * w[lane + 64];

    const float inv_freq = expf(-(float)lane * (logf(10000.0f) / 64.0f));
    const float ang = (float)s * inv_freq;
    const float c = cosf(ang);
    const float sn = sinf(ang);
    base[lane]      = f2bf(x0 * c - x1 * sn);
    base[lane + 64] = f2bf(x1 * c + x0 * sn);
}

// ---------------------------------------------------------------------------
// Transpose V (bf16): qkv[token][2560 + kvh*128 + d] -> vT[b][kvh][d][s]
// ---------------------------------------------------------------------------
__global__ __launch_bounds__(256)
void transpose_v(const short* __restrict__ qkv, short* __restrict__ vT)
{
    __shared__ short T[32][33];
    const int bx = blockIdx.x;          // 8 * 4 * 64 = 2048
    const int st = bx & 63;
    const int dt = (bx >> 6) & 3;
    const int bk = bx >> 8;             // b*NKV+kvh, 0..7
    const int s0 = st * 32, d0 = dt * 32;
    const int tid = threadIdx.x;
    const long tok0 = (long)(bk >> 2) * SEQ + s0;
    const int kvh = bk & 3;

    const int rs = tid >> 3;            // 0..31 (s row)
    const int rc = (tid & 7) * 4;       // 0..28 (d col base)
    short4v val = *(const short4v*)(qkv + (tok0 + rs) * QKV + 2560 + kvh * HD + d0 + rc);
    T[rc + 0][rs] = val.x; T[rc + 1][rs] = val.y;
    T[rc + 2][rs] = val.z; T[rc + 3][rs] = val.w;
    __syncthreads();

    const int wd = tid >> 3;            // d row
    const int wsc = (tid & 7) * 4;      // s col base
    short4v ov;
    ov.x = T[wd][wsc + 0]; ov.y = T[wd][wsc + 1];
    ov.z = T[wd][wsc + 2]; ov.w = T[wd][wsc + 3];
    *(short4v*)(vT + ((size_t)bk * HD + d0 + wd) * SEQ + s0 + wsc) = ov;
}

// ---------------------------------------------------------------------------
// Flash-style causal GQA attention, bf16 MFMA, fp32 accumulate.
// Block = 4 waves = (b,h,64 q rows); wave = 16 q rows. All-bf16 inputs.
// Output written bf16 to o[token][h*128+d] (feeds O-proj GEMM as A operand).
// ---------------------------------------------------------------------------
__global__ __launch_bounds__(256)
void flash_attn_mfma(const short* __restrict__ qkv, const short* __restrict__ vT,
                     short* __restrict__ o)
{
    __shared__ short Ks[32][136];      // [key][d]  padded (2-way = free)
    __shared__ short Vt[128][40];      // [d][key]
    __shared__ short Ps[4][16][40];    // per-wave P tile [qrow][key]

    const int tid = threadIdx.x;
    const int w = tid >> 6;
    const int lane = tid & 63;
    const int quad = lane >> 4;
    const int ln = lane & 15;

    const int bx = blockIdx.x;
    const int qt = 31 - (bx >> 5);     // heaviest q-tiles first
    const int h = bx & 15;
    const int b = (bx >> 4) & 1;
    const int kvh = h >> 2;
    const int q0 = qt * 64;
    const int r0 = q0 + w * 16;

    const float sc = 0.08838834764831845f * 1.4426950408889634f; // 1/sqrt(HD)*log2e

    // Q -> A-frags (raw bf16; scale applied post-MFMA)
    bf16x8 qf[4];
    const short* qrow = qkv + (size_t)(b * SEQ + r0 + ln) * QKV + h * HD;
    #pragma unroll
    for (int f = 0; f < 4; ++f)
        qf[f] = *(const bf16x8*)(qrow + f * 32 + quad * 8);

    f32x4 Oa[8];
    #pragma unroll
    for (int dg = 0; dg < 8; ++dg) Oa[dg] = (f32x4){0.f, 0.f, 0.f, 0.f};
    float mrow[4] = {-1e30f, -1e30f, -1e30f, -1e30f};
    float lrow[4] = {0.f, 0.f, 0.f, 0.f};

    const short* kbase = qkv + (size_t)(b * SEQ) * QKV + 2048 + kvh * HD;
    const short* vbase = vT + (size_t)(b * NKV + kvh) * HD * SEQ;

    const int nkt = (q0 + 64) >> 5;
    for (int kt = 0; kt < nkt; ++kt) {
        const int k0 = kt * 32;
        __syncthreads();
        // stage K tile: 32 keys x 16 groups of 8 bf16 = 512 units, 2/thread
        #pragma unroll
        for (int i = 0; i < 2; ++i) {
            int e = tid + i * 256;
            int key = e >> 4;
            int d0 = (e & 15) * 8;
            *(bf16x8*)&Ks[key][d0] =
                *(const bf16x8*)(kbase + (size_t)(k0 + key) * QKV + d0);
        }
        // stage V^T tile: 128 d x 4 groups of 8 = 512 units, 2/thread
        #pragma unroll
        for (int i = 0; i < 2; ++i) {
            int e = tid + i * 256;
            int d = e >> 2;
            int kg = (e & 3) * 8;
            *(bf16x8*)&Vt[d][kg] =
                *(const bf16x8*)(vbase + (size_t)d * SEQ + k0 + kg);
        }
        __syncthreads();

        if (k0 <= r0 + 15) {
            // QK^T
            f32x4 s[2];
            #pragma unroll
            for (int g = 0; g < 2; ++g) {
                f32x4 acc = (f32x4){0.f, 0.f, 0.f, 0.f};
                #pragma unroll
                for (int f = 0; f < 4; ++f) {
                    bf16x8 kf = *(const bf16x8*)&Ks[g * 16 + ln][f * 32 + quad * 8];
                    acc = __builtin_amdgcn_mfma_f32_16x16x32_bf16(qf[f], kf, acc, 0, 0, 0);
                }
                #pragma unroll
                for (int reg = 0; reg < 4; ++reg) acc[reg] *= sc;
                s[g] = acc;
            }

            // causal mask (diagonal tiles only)
            if (k0 + 31 > r0) {
                #pragma unroll
                for (int g = 0; g < 2; ++g) {
                    const int keyg = k0 + g * 16 + ln;
                    #pragma unroll
                    for (int reg = 0; reg < 4; ++reg) {
                        const int rowg = r0 + quad * 4 + reg;
                        if (keyg > rowg) s[g][reg] = -1e30f;
                    }
                }
            }

            // online softmax (exp2 domain)
            float alpha4[4];
            #pragma unroll
            for (int reg = 0; reg < 4; ++reg) {
                float mx = fmaxf(s[0][reg], s[1][reg]);
                mx = fmaxf(mx, __shfl_xor(mx, 1, 64));
                mx = fmaxf(mx, __shfl_xor(mx, 2, 64));
                mx = fmaxf(mx, __shfl_xor(mx, 4, 64));
                mx = fmaxf(mx, __shfl_xor(mx, 8, 64));
                const float mnew = fmaxf(mrow[reg], mx);
                const float alpha = exp2f(mrow[reg] - mnew);
                const float p0 = exp2f(s[0][reg] - mnew);
                const float p1 = exp2f(s[1][reg] - mnew);
                float ps = p0 + p1;
                ps += __shfl_xor(ps, 1, 64);
                ps += __shfl_xor(ps, 2, 64);
                ps += __shfl_xor(ps, 4, 64);
                ps += __shfl_xor(ps, 8, 64);
                lrow[reg] = lrow[reg] * alpha + ps;
                mrow[reg] = mnew;
                alpha4[reg] = alpha;
                Ps[w][quad * 4 + reg][ln]      = f2bf(p0);
                Ps[w][quad * 4 + reg][16 + ln] = f2bf(p1);
            }
            #pragma unroll
            for (int dg = 0; dg < 8; ++dg) {
                Oa[dg][0] *= alpha4[0]; Oa[dg][1] *= alpha4[1];
                Oa[dg][2] *= alpha4[2]; Oa[dg][3] *= alpha4[3];
            }

            __asm volatile("s_waitcnt lgkmcnt(0)" ::: "memory");

            // PV
            bf16x8 pf = *(const bf16x8*)&Ps[w][ln][quad * 8];
            #pragma unroll
            for (int dg = 0; dg < 8; ++dg) {
                bf16x8 vf = *(const bf16x8*)&Vt[dg * 16 + ln][quad * 8];
                Oa[dg] = __builtin_amdgcn_mfma_f32_16x16x32_bf16(pf, vf, Oa[dg], 0, 0, 0);
            }
        }
    }

    // epilogue: bf16 out, layout [token][h*128 + d]
    #pragma unroll
    for (int reg = 0; reg < 4; ++reg) {
        const float inv = 1.0f / lrow[reg];
        const int row = r0 + quad * 4 + reg;
        short* orow = o + ((size_t)(b * SEQ + row) * NH + h) * HD;
        #pragma unroll
        for (int dg = 0; dg < 8; ++dg)
            orow[dg * 16 + ln] = f2bf(Oa[dg][reg] * inv);
    }
}

// ---------------------------------------------------------------------------
extern "C" void kernel_launch(void* const* d_in, const int* in_sizes, int n_in,
                              void* d_out, int out_size, void* d_ws, size_t ws_size,
                              hipStream_t stream)
{
    const float* hs = (const float*)d_in[0];
    const float* Wq = (const float*)d_in[2];
    const float* Wk = (const float*)d_in[3];
    const float* Wv = (const float*)d_in[4];
    const float* Wo = (const float*)d_in[5];
    const float* qw = (const float*)d_in[6];
    const float* kw = (const float*)d_in[7];
    float* out = (float*)d_out;

    const size_t MEG = 1024 * 1024;
    short* hsb  = (short*)d_ws;          // 8M bf16: hs; later reused as attn-out
    short* wqkv = hsb + 8 * MEG;         // 6M bf16: Wq|Wk|Wv fused [3072][2048]
    short* wob  = wqkv + 6 * MEG;        // 4M bf16: Wo
    short* qkvb = wob + 4 * MEG;         // 12M bf16: fused qkv [4096][3072]
    short* vT   = (short*)d_out;         // 4M bf16 in d_out (dead until O-proj)
    // ws use: 30M shorts = 60 MB

    const int M = BATCH * SEQ;           // 4096
    dim3 blk(256);

    // casts
    cast_f32_bf16<<<dim3(8192), blk, 0, stream>>>(hs, hsb);
    cast_f32_bf16<<<dim3(4096), blk, 0, stream>>>(Wq, wqkv);
    cast_f32_bf16<<<dim3(1024), blk, 0, stream>>>(Wk, wqkv + 4 * MEG);
    cast_f32_bf16<<<dim3(1024), blk, 0, stream>>>(Wv, wqkv + 5 * MEG);
    cast_f32_bf16<<<dim3(4096), blk, 0, stream>>>(Wo, wob);

    // fused QKV projection: [4096,2048] @ [3072,2048]^T -> bf16 [4096,3072]
    gemm_nt_mfma<true><<<dim3(QKV / 128, M / 128), blk, 0, stream>>>(
        hsb, wqkv, qkvb, M, QKV, 2048);

    // RMSNorm + RoPE on q,k portions (in place)
    norm_rope_bf16<<<dim3((BATCH * SEQ * (NH + NKV)) / 4), blk, 0, stream>>>(
        qkvb, qw, kw);

    // V transpose for PV B-operand layout
    transpose_v<<<dim3(2048), blk, 0, stream>>>(qkvb, vT);

    // causal GQA flash attention -> bf16 attn-out into hsb
    flash_attn_mfma<<<dim3(BATCH * NH * (SEQ / 64)), blk, 0, stream>>>(
        qkvb, vT, hsb);

    // output projection: [4096,2048]bf16 @ [2048,2048]^T -> fp32 out
    gemm_nt_mfma<false><<<dim3(2048 / 128, M / 128), blk, 0, stream>>>(
        hsb, wob, out, M, 2048, 2048);
}

// Round 5
// 366.688 us; speedup vs baseline: 9.8466x; 1.1454x over previous
//
#include <hip/hip_runtime.h>
#include <math.h>

#define NH 16
#define NKV 4
#define HD 128
#define SEQ 2048
#define BATCH 2
#define EPSF 1e-6f
#define QKV 3072      // fused projection width: 2048 q | 512 k | 512 v

typedef __attribute__((ext_vector_type(8))) short bf16x8;
typedef __attribute__((ext_vector_type(4))) short short4v;
typedef __attribute__((ext_vector_type(4))) float f32x4;

__device__ __forceinline__ short f2bf(float x) {
    unsigned u = __float_as_uint(x);
    u += 0x7fffu + ((u >> 16) & 1u);      // round-to-nearest-even
    return (short)(u >> 16);
}
__device__ __forceinline__ float bf2f(short x) {
    return __uint_as_float((unsigned)(unsigned short)x << 16);
}

// async global->LDS, 16B per lane; LDS dest = wave-uniform base + lane*16
__device__ __forceinline__ void gll16(const short* g, short* l) {
    __builtin_amdgcn_global_load_lds(
        (const __attribute__((address_space(1))) unsigned*)g,
        (__attribute__((address_space(3))) unsigned*)l, 16, 0, 0);
}

// ---------------------------------------------------------------------------
// Fused fp32->bf16 casts: hs(8M)->hsb, Wq(4M)|Wk(1M)|Wv(1M)->wqkv, Wo(4M)->wob
// ---------------------------------------------------------------------------
__global__ __launch_bounds__(256)
void cast_all(const float* __restrict__ hs, const float* __restrict__ Wq,
              const float* __restrict__ Wk, const float* __restrict__ Wv,
              const float* __restrict__ Wo, short* __restrict__ hsb,
              short* __restrict__ wqkv, short* __restrict__ wob)
{
    const size_t MEG = 1024 * 1024;
    const int id = blockIdx.x;
    const float* s;
    short* d;
    size_t off;
    if (id < 8192)       { s = hs; d = hsb;            off = (size_t)id * 1024; }
    else if (id < 12288) { s = Wq; d = wqkv;           off = (size_t)(id - 8192) * 1024; }
    else if (id < 13312) { s = Wk; d = wqkv + 4 * MEG; off = (size_t)(id - 12288) * 1024; }
    else if (id < 14336) { s = Wv; d = wqkv + 5 * MEG; off = (size_t)(id - 13312) * 1024; }
    else                 { s = Wo; d = wob;            off = (size_t)(id - 14336) * 1024; }
    const size_t i = off + threadIdx.x * 4;
    float4 v = *(const float4*)(s + i);
    short4v o;
    o.x = f2bf(v.x); o.y = f2bf(v.y); o.z = f2bf(v.z); o.w = f2bf(v.w);
    *(short4v*)(d + i) = o;
}

// ---------------------------------------------------------------------------
// bf16 MFMA GEMM NT: C[M,N] = A[M,K] @ B[N,K]^T, fp32 accum. (m97 structure)
// ---------------------------------------------------------------------------
template<bool OUT_BF16>
__global__ __launch_bounds__(256)
void gemm_nt_mfma(const short* __restrict__ A, const short* __restrict__ B,
                  void* __restrict__ Cv, int M, int N, int K)
{
    __shared__ short As[128 * 32];
    __shared__ short Bs[128 * 32];

    const int tid = threadIdx.x;
    const int w = tid >> 6, lane = tid & 63;
    const int quad = lane >> 4, ln = lane & 15;
    const int mw = (w >> 1) * 64, nw = (w & 1) * 64;
    const int m0 = blockIdx.y * 128, n0 = blockIdx.x * 128;

    const int srow = w * 16 + (lane >> 2);
    const int scol = (lane & 3) * 8;
    const short* Ag0 = A + (size_t)(m0 + srow) * K + scol;
    const short* Ag1 = Ag0 + (size_t)64 * K;
    const short* Bg0 = B + (size_t)(n0 + srow) * K + scol;
    const short* Bg1 = Bg0 + (size_t)64 * K;
    short* Al0 = &As[(w * 16) * 32];
    short* Al1 = &As[(w * 16 + 64) * 32];
    short* Bl0 = &Bs[(w * 16) * 32];
    short* Bl1 = &Bs[(w * 16 + 64) * 32];

    f32x4 acc[4][4];
    #pragma unroll
    for (int i = 0; i < 4; ++i)
        #pragma unroll
        for (int j = 0; j < 4; ++j)
            acc[i][j] = (f32x4){0.f, 0.f, 0.f, 0.f};

    for (int k0 = 0; k0 < K; k0 += 32) {
        __syncthreads();
        gll16(Ag0 + k0, Al0);
        gll16(Ag1 + k0, Al1);
        gll16(Bg0 + k0, Bl0);
        gll16(Bg1 + k0, Bl1);
        __syncthreads();

        bf16x8 af[4], bfr[4];
        #pragma unroll
        for (int i = 0; i < 4; ++i)
            af[i] = *(const bf16x8*)&As[(mw + i * 16 + ln) * 32 + quad * 8];
        #pragma unroll
        for (int j = 0; j < 4; ++j)
            bfr[j] = *(const bf16x8*)&Bs[(nw + j * 16 + ln) * 32 + quad * 8];
        #pragma unroll
        for (int i = 0; i < 4; ++i)
            #pragma unroll
            for (int j = 0; j < 4; ++j)
                acc[i][j] = __builtin_amdgcn_mfma_f32_16x16x32_bf16(
                    af[i], bfr[j], acc[i][j], 0, 0, 0);
    }

    #pragma unroll
    for (int i = 0; i < 4; ++i) {
        #pragma unroll
        for (int reg = 0; reg < 4; ++reg) {
            const int row = m0 + mw + i * 16 + quad * 4 + reg;
            const size_t base = (size_t)row * N + n0 + nw;
            #pragma unroll
            for (int j = 0; j < 4; ++j) {
                if (OUT_BF16)
                    ((short*)Cv)[base + j * 16 + ln] = f2bf(acc[i][j][reg]);
                else
                    ((float*)Cv)[base + j * 16 + ln] = acc[i][j][reg];
            }
        }
    }
}

// ---------------------------------------------------------------------------
// Fused RMSNorm + RoPE on bf16 qkv[token][3072], in place (fp32 math).
// ---------------------------------------------------------------------------
__global__ __launch_bounds__(256)
void norm_rope_bf16(short* __restrict__ qkv, const float* __restrict__ qw,
                    const float* __restrict__ kw)
{
    const int wave = threadIdx.x >> 6;
    const int lane = threadIdx.x & 63;
    const long vec = (long)blockIdx.x * 4 + wave;
    const long NQ = (long)BATCH * SEQ * NH;

    short* base;
    const float* w;
    int s;
    if (vec < NQ) {
        const long token = vec / NH;
        const int h = (int)(vec % NH);
        s = (int)(token % SEQ);
        base = qkv + token * QKV + h * HD;
        w = qw;
    } else {
        const long t = vec - NQ;
        const long token = t / NKV;
        const int kvh = (int)(t % NKV);
        s = (int)(token % SEQ);
        base = qkv + token * QKV + 2048 + kvh * HD;
        w = kw;
    }

    float x0 = bf2f(base[lane]);
    float x1 = bf2f(base[lane + 64]);
    float ss = x0 * x0 + x1 * x1;
    #pragma unroll
    for (int off = 32; off; off >>= 1) ss += __shfl_xor(ss, off, 64);
    const float r = rsqrtf(ss * (1.0f / HD) + EPSF);
    x0 = x0 * r * w[lane];
    x1 = x1 * r * w[lane + 64];

    const float inv_freq = expf(-(float)lane * (logf(10000.0f) / 64.0f));
    const float ang = (float)s * inv_freq;
    const float c = cosf(ang);
    const float sn = sinf(ang);
    base[lane]      = f2bf(x0 * c - x1 * sn);
    base[lane + 64] = f2bf(x1 * c + x0 * sn);
}

// ---------------------------------------------------------------------------
// Transpose V (bf16): qkv[token][2560 + kvh*128 + d] -> vT[b][kvh][d][s]
// ---------------------------------------------------------------------------
__global__ __launch_bounds__(256)
void transpose_v(const short* __restrict__ qkv, short* __restrict__ vT)
{
    __shared__ short T[32][33];
    const int bx = blockIdx.x;
    const int st = bx & 63;
    const int dt = (bx >> 6) & 3;
    const int bk = bx >> 8;
    const int s0 = st * 32, d0 = dt * 32;
    const int tid = threadIdx.x;
    const long tok0 = (long)(bk >> 2) * SEQ + s0;
    const int kvh = bk & 3;

    const int rs = tid >> 3;
    const int rc = (tid & 7) * 4;
    short4v val = *(const short4v*)(qkv + (tok0 + rs) * QKV + 2560 + kvh * HD + d0 + rc);
    T[rc + 0][rs] = val.x; T[rc + 1][rs] = val.y;
    T[rc + 2][rs] = val.z; T[rc + 3][rs] = val.w;
    __syncthreads();

    const int wd = tid >> 3;
    const int wsc = (tid & 7) * 4;
    short4v ov;
    ov.x = T[wd][wsc + 0]; ov.y = T[wd][wsc + 1];
    ov.z = T[wd][wsc + 2]; ov.w = T[wd][wsc + 3];
    *(short4v*)(vT + ((size_t)bk * HD + d0 + wd) * SEQ + s0 + wsc) = ov;
}

// ---------------------------------------------------------------------------
// Flash causal GQA attention v2, bf16 MFMA, fp32 accum.
// Swapped operands: scores = K@Q^T (q = lane ln -> per-lane softmax state),
// PV as O^T = V^T @ P^T. 64-key K-tiles. Block = q-tile PAIR (qa, 31-qa):
// every block does exactly 33 subtile-units of MFMA work and shares staging.
// Grid = 16 pairs x 32 (b,h) = 512 blocks = 2/CU.
// ---------------------------------------------------------------------------
__global__ __launch_bounds__(256)
void flash_attn_mfma(const short* __restrict__ qkv, const short* __restrict__ vT,
                     short* __restrict__ o)
{
    __shared__ short Ks[64][144];      // [key][d]   288B rows (16B-aligned)
    __shared__ short Vt[128][80];      // [d][key]   160B rows
    __shared__ short Ps[4][16][80];    // per-wave [q][key]

    const int tid = threadIdx.x;
    const int w = tid >> 6;
    const int lane = tid & 63;
    const int quad = lane >> 4;
    const int ln = lane & 15;

    const int bx = blockIdx.x;
    const int pair = bx & 15;
    const int bh = bx >> 4;
    const int h = bh & 15;
    const int b = bh >> 4;
    const int kvh = h >> 2;
    const int qa = pair, qb = 31 - pair;
    const int rA = qa * 64 + w * 16;
    const int rB = qb * 64 + w * 16;

    const float SC = 0.08838834764831845f * 1.4426950408889634f; // 1/sqrt(HD)*log2e

    // Q -> B-frags for both subtiles (lane ln = q row)
    bf16x8 qfA[4], qfB[4];
    {
        const short* qra = qkv + (size_t)(b * SEQ + rA + ln) * QKV + h * HD;
        const short* qrb = qkv + (size_t)(b * SEQ + rB + ln) * QKV + h * HD;
        #pragma unroll
        for (int f = 0; f < 4; ++f) {
            qfA[f] = *(const bf16x8*)(qra + f * 32 + quad * 8);
            qfB[f] = *(const bf16x8*)(qrb + f * 32 + quad * 8);
        }
    }

    f32x4 OaA[8], OaB[8];
    #pragma unroll
    for (int dg = 0; dg < 8; ++dg) {
        OaA[dg] = (f32x4){0.f, 0.f, 0.f, 0.f};
        OaB[dg] = (f32x4){0.f, 0.f, 0.f, 0.f};
    }
    float mA = -1e30f, lA = 0.f, mB = -1e30f, lB = 0.f;

    const short* kbase = qkv + (size_t)(b * SEQ) * QKV + 2048 + kvh * HD;
    const short* vbase = vT + (size_t)(b * NKV + kvh) * HD * SEQ;

    // one softmax+PV pass for a q-subtile against the staged 64-key tile
    auto process = [&](int k0, int rX, float& mX, float& lX,
                       const bf16x8* qf, f32x4* Oa) {
        if (k0 > rX + 15) return;
        // K@Q^T: D[key = quad*4+reg (+16g)][q = ln]
        f32x4 s[4];
        #pragma unroll
        for (int g = 0; g < 4; ++g) {
            f32x4 acc = (f32x4){0.f, 0.f, 0.f, 0.f};
            #pragma unroll
            for (int f = 0; f < 4; ++f) {
                bf16x8 kf = *(const bf16x8*)&Ks[g * 16 + ln][f * 32 + quad * 8];
                acc = __builtin_amdgcn_mfma_f32_16x16x32_bf16(kf, qf[f], acc, 0, 0, 0);
            }
            s[g] = acc;
        }
        // causal mask (diagonal tiles only); q = rX + ln per lane
        if (k0 + 63 > rX) {
            const int qrow = rX + ln;
            #pragma unroll
            for (int g = 0; g < 4; ++g) {
                #pragma unroll
                for (int reg = 0; reg < 4; ++reg) {
                    const int key = k0 + g * 16 + quad * 4 + reg;
                    if (key > qrow) s[g][reg] = -1e30f;
                }
            }
        }
        // per-lane online softmax (16 scores/lane); cross-quad combine
        float mt = s[0][0];
        #pragma unroll
        for (int g = 0; g < 4; ++g)
            #pragma unroll
            for (int reg = 0; reg < 4; ++reg)
                mt = fmaxf(mt, s[g][reg]);
        mt = fmaxf(mt, __shfl_xor(mt, 16, 64));
        mt = fmaxf(mt, __shfl_xor(mt, 32, 64));
        const float mnew = fmaxf(mX, mt);
        const float c1 = SC * mnew;
        const float alpha = exp2f(__builtin_fmaf(SC, mX, -c1));
        float ps = 0.f;
        #pragma unroll
        for (int g = 0; g < 4; ++g) {
            float p0 = exp2f(__builtin_fmaf(s[g][0], SC, -c1));
            float p1 = exp2f(__builtin_fmaf(s[g][1], SC, -c1));
            float p2 = exp2f(__builtin_fmaf(s[g][2], SC, -c1));
            float p3 = exp2f(__builtin_fmaf(s[g][3], SC, -c1));
            ps += (p0 + p1) + (p2 + p3);
            short4v pk;
            pk.x = f2bf(p0); pk.y = f2bf(p1); pk.z = f2bf(p2); pk.w = f2bf(p3);
            *(short4v*)&Ps[w][ln][g * 16 + quad * 4] = pk;   // 8B ds_write
        }
        ps += __shfl_xor(ps, 16, 64);
        ps += __shfl_xor(ps, 32, 64);
        lX = lX * alpha + ps;
        mX = mnew;
        #pragma unroll
        for (int dg = 0; dg < 8; ++dg) {
            Oa[dg][0] *= alpha; Oa[dg][1] *= alpha;
            Oa[dg][2] *= alpha; Oa[dg][3] *= alpha;
        }
        __asm volatile("s_waitcnt lgkmcnt(0)" ::: "memory");
        // O^T = V^T @ P^T: D[d = quad*4+reg (+16dg)][q = ln]
        bf16x8 pf0 = *(const bf16x8*)&Ps[w][ln][quad * 8];
        bf16x8 pf1 = *(const bf16x8*)&Ps[w][ln][32 + quad * 8];
        #pragma unroll
        for (int dg = 0; dg < 8; ++dg) {
            bf16x8 vf0 = *(const bf16x8*)&Vt[dg * 16 + ln][quad * 8];
            bf16x8 vf1 = *(const bf16x8*)&Vt[dg * 16 + ln][32 + quad * 8];
            Oa[dg] = __builtin_amdgcn_mfma_f32_16x16x32_bf16(vf0, pf0, Oa[dg], 0, 0, 0);
            Oa[dg] = __builtin_amdgcn_mfma_f32_16x16x32_bf16(vf1, pf1, Oa[dg], 0, 0, 0);
        }
    };

    for (int kt = 0; kt <= qb; ++kt) {
        const int k0 = kt * 64;
        __syncthreads();
        // stage K: 64 keys x 16 bf16x8 units = 1024, 4/thread
        #pragma unroll
        for (int i = 0; i < 4; ++i) {
            const int e = tid + i * 256;
            const int key = e >> 4;
            const int dg = (e & 15) * 8;
            *(bf16x8*)&Ks[key][dg] =
                *(const bf16x8*)(kbase + (size_t)(k0 + key) * QKV + dg);
        }
        // stage V^T: 128 d x 8 bf16x8 units = 1024, 4/thread
        #pragma unroll
        for (int i = 0; i < 4; ++i) {
            const int e = tid + i * 256;
            const int d = e >> 3;
            const int kg = (e & 7) * 8;
            *(bf16x8*)&Vt[d][kg] =
                *(const bf16x8*)(vbase + (size_t)d * SEQ + k0 + kg);
        }
        __syncthreads();

        process(k0, rA, mA, lA, qfA, OaA);
        process(k0, rB, mB, lB, qfB, OaB);
    }

    // epilogue: lane owns q-row rX+ln entirely; d = dg*16 + quad*4 + {0..3}
    {
        const float invA = 1.0f / lA;
        const float invB = 1.0f / lB;
        short* orA = o + ((size_t)(b * SEQ + rA + ln) * NH + h) * HD;
        short* orB = o + ((size_t)(b * SEQ + rB + ln) * NH + h) * HD;
        #pragma unroll
        for (int dg = 0; dg < 8; ++dg) {
            short4v oa, ob;
            oa.x = f2bf(OaA[dg][0] * invA); oa.y = f2bf(OaA[dg][1] * invA);
            oa.z = f2bf(OaA[dg][2] * invA); oa.w = f2bf(OaA[dg][3] * invA);
            ob.x = f2bf(OaB[dg][0] * invB); ob.y = f2bf(OaB[dg][1] * invB);
            ob.z = f2bf(OaB[dg][2] * invB); ob.w = f2bf(OaB[dg][3] * invB);
            *(short4v*)(orA + dg * 16 + quad * 4) = oa;
            *(short4v*)(orB + dg * 16 + quad * 4) = ob;
        }
    }
}

// ---------------------------------------------------------------------------
extern "C" void kernel_launch(void* const* d_in, const int* in_sizes, int n_in,
                              void* d_out, int out_size, void* d_ws, size_t ws_size,
                              hipStream_t stream)
{
    const float* hs = (const float*)d_in[0];
    const float* Wq = (const float*)d_in[2];
    const float* Wk = (const float*)d_in[3];
    const float* Wv = (const float*)d_in[4];
    const float* Wo = (const float*)d_in[5];
    const float* qw = (const float*)d_in[6];
    const float* kw = (const float*)d_in[7];
    float* out = (float*)d_out;

    const size_t MEG = 1024 * 1024;
    short* hsb  = (short*)d_ws;          // 8M bf16: hs; later reused as attn-out
    short* wqkv = hsb + 8 * MEG;         // 6M bf16: Wq|Wk|Wv fused [3072][2048]
    short* wob  = wqkv + 6 * MEG;        // 4M bf16: Wo
    short* qkvb = wob + 4 * MEG;         // 12M bf16: fused qkv [4096][3072]
    short* vT   = (short*)d_out;         // 4M bf16 in d_out (dead until O-proj)

    const int M = BATCH * SEQ;           // 4096
    dim3 blk(256);

    cast_all<<<dim3(18432), blk, 0, stream>>>(hs, Wq, Wk, Wv, Wo, hsb, wqkv, wob);

    gemm_nt_mfma<true><<<dim3(QKV / 128, M / 128), blk, 0, stream>>>(
        hsb, wqkv, qkvb, M, QKV, 2048);

    norm_rope_bf16<<<dim3((BATCH * SEQ * (NH + NKV)) / 4), blk, 0, stream>>>(
        qkvb, qw, kw);

    transpose_v<<<dim3(2048), blk, 0, stream>>>(qkvb, vT);

    flash_attn_mfma<<<dim3(512), blk, 0, stream>>>(qkvb, vT, hsb);

    gemm_nt_mfma<false><<<dim3(2048 / 128, M / 128), blk, 0, stream>>>(
        hsb, wob, out, M, 2048, 2048);
}

// Round 6
// 358.384 us; speedup vs baseline: 10.0748x; 1.0232x over previous
//
#include <hip/hip_runtime.h>
#include <hip/hip_bf16.h>
#include <math.h>

#define NH 16
#define NKV 4
#define HD 128
#define SEQ 2048
#define BATCH 2
#define EPSF 1e-6f
#define QKV 3072      // fused projection width: 2048 q | 512 k | 512 v

typedef __attribute__((ext_vector_type(8))) short bf16x8;
typedef __attribute__((ext_vector_type(4))) short short4v;
typedef __attribute__((ext_vector_type(4))) float f32x4;

__device__ __forceinline__ short f2bf(float x) {
    unsigned u = __float_as_uint(x);
    u += 0x7fffu + ((u >> 16) & 1u);      // round-to-nearest-even
    return (short)(u >> 16);
}
__device__ __forceinline__ float bf2f(short x) {
    return __uint_as_float((unsigned)(unsigned short)x << 16);
}
// packed f32x2 -> bf16x2 (v_cvt_pk_bf16_f32), RNE
__device__ __forceinline__ unsigned pkbf(float a, float b) {
    __hip_bfloat162 h = __float22bfloat162_rn(float2{a, b});
    unsigned r; __builtin_memcpy(&r, &h, 4); return r;
}

// async global->LDS, 16B per lane; LDS dest = wave-uniform base + lane*16
__device__ __forceinline__ void gll16(const short* g, short* l) {
    __builtin_amdgcn_global_load_lds(
        (const __attribute__((address_space(1))) unsigned*)g,
        (__attribute__((address_space(3))) unsigned*)l, 16, 0, 0);
}

// ---------------------------------------------------------------------------
// Fused fp32->bf16 casts: hs(8M)->hsb, Wq(4M)|Wk(1M)|Wv(1M)->wqkv, Wo(4M)->wob
// ---------------------------------------------------------------------------
__global__ __launch_bounds__(256)
void cast_all(const float* __restrict__ hs, const float* __restrict__ Wq,
              const float* __restrict__ Wk, const float* __restrict__ Wv,
              const float* __restrict__ Wo, short* __restrict__ hsb,
              short* __restrict__ wqkv, short* __restrict__ wob)
{
    const size_t MEG = 1024 * 1024;
    const int id = blockIdx.x;
    const float* s;
    short* d;
    size_t off;
    if (id < 8192)       { s = hs; d = hsb;            off = (size_t)id * 1024; }
    else if (id < 12288) { s = Wq; d = wqkv;           off = (size_t)(id - 8192) * 1024; }
    else if (id < 13312) { s = Wk; d = wqkv + 4 * MEG; off = (size_t)(id - 12288) * 1024; }
    else if (id < 14336) { s = Wv; d = wqkv + 5 * MEG; off = (size_t)(id - 13312) * 1024; }
    else                 { s = Wo; d = wob;            off = (size_t)(id - 14336) * 1024; }
    const size_t i = off + threadIdx.x * 4;
    float4 v = *(const float4*)(s + i);
    short4v o;
    o.x = f2bf(v.x); o.y = f2bf(v.y); o.z = f2bf(v.z); o.w = f2bf(v.w);
    *(short4v*)(d + i) = o;
}

// ---------------------------------------------------------------------------
// bf16 MFMA GEMM NT: C[M,N] = A[M,K] @ B[N,K]^T, fp32 accum. (m97 structure)
// ---------------------------------------------------------------------------
template<bool OUT_BF16>
__global__ __launch_bounds__(256)
void gemm_nt_mfma(const short* __restrict__ A, const short* __restrict__ B,
                  void* __restrict__ Cv, int M, int N, int K)
{
    __shared__ short As[128 * 32];
    __shared__ short Bs[128 * 32];

    const int tid = threadIdx.x;
    const int w = tid >> 6, lane = tid & 63;
    const int quad = lane >> 4, ln = lane & 15;
    const int mw = (w >> 1) * 64, nw = (w & 1) * 64;
    const int m0 = blockIdx.y * 128, n0 = blockIdx.x * 128;

    const int srow = w * 16 + (lane >> 2);
    const int scol = (lane & 3) * 8;
    const short* Ag0 = A + (size_t)(m0 + srow) * K + scol;
    const short* Ag1 = Ag0 + (size_t)64 * K;
    const short* Bg0 = B + (size_t)(n0 + srow) * K + scol;
    const short* Bg1 = Bg0 + (size_t)64 * K;
    short* Al0 = &As[(w * 16) * 32];
    short* Al1 = &As[(w * 16 + 64) * 32];
    short* Bl0 = &Bs[(w * 16) * 32];
    short* Bl1 = &Bs[(w * 16 + 64) * 32];

    f32x4 acc[4][4];
    #pragma unroll
    for (int i = 0; i < 4; ++i)
        #pragma unroll
        for (int j = 0; j < 4; ++j)
            acc[i][j] = (f32x4){0.f, 0.f, 0.f, 0.f};

    for (int k0 = 0; k0 < K; k0 += 32) {
        __syncthreads();
        gll16(Ag0 + k0, Al0);
        gll16(Ag1 + k0, Al1);
        gll16(Bg0 + k0, Bl0);
        gll16(Bg1 + k0, Bl1);
        __syncthreads();

        bf16x8 af[4], bfr[4];
        #pragma unroll
        for (int i = 0; i < 4; ++i)
            af[i] = *(const bf16x8*)&As[(mw + i * 16 + ln) * 32 + quad * 8];
        #pragma unroll
        for (int j = 0; j < 4; ++j)
            bfr[j] = *(const bf16x8*)&Bs[(nw + j * 16 + ln) * 32 + quad * 8];
        #pragma unroll
        for (int i = 0; i < 4; ++i)
            #pragma unroll
            for (int j = 0; j < 4; ++j)
                acc[i][j] = __builtin_amdgcn_mfma_f32_16x16x32_bf16(
                    af[i], bfr[j], acc[i][j], 0, 0, 0);
    }

    #pragma unroll
    for (int i = 0; i < 4; ++i) {
        #pragma unroll
        for (int reg = 0; reg < 4; ++reg) {
            const int row = m0 + mw + i * 16 + quad * 4 + reg;
            const size_t base = (size_t)row * N + n0 + nw;
            #pragma unroll
            for (int j = 0; j < 4; ++j) {
                if (OUT_BF16)
                    ((short*)Cv)[base + j * 16 + ln] = f2bf(acc[i][j][reg]);
                else
                    ((float*)Cv)[base + j * 16 + ln] = acc[i][j][reg];
            }
        }
    }
}

// ---------------------------------------------------------------------------
// Fused RMSNorm + RoPE on bf16 qkv[token][3072], in place (fp32 math).
// ---------------------------------------------------------------------------
__global__ __launch_bounds__(256)
void norm_rope_bf16(short* __restrict__ qkv, const float* __restrict__ qw,
                    const float* __restrict__ kw)
{
    const int wave = threadIdx.x >> 6;
    const int lane = threadIdx.x & 63;
    const long vec = (long)blockIdx.x * 4 + wave;
    const long NQ = (long)BATCH * SEQ * NH;

    short* base;
    const float* w;
    int s;
    if (vec < NQ) {
        const long token = vec / NH;
        const int h = (int)(vec % NH);
        s = (int)(token % SEQ);
        base = qkv + token * QKV + h * HD;
        w = qw;
    } else {
        const long t = vec - NQ;
        const long token = t / NKV;
        const int kvh = (int)(t % NKV);
        s = (int)(token % SEQ);
        base = qkv + token * QKV + 2048 + kvh * HD;
        w = kw;
    }

    float x0 = bf2f(base[lane]);
    float x1 = bf2f(base[lane + 64]);
    float ss = x0 * x0 + x1 * x1;
    #pragma unroll
    for (int off = 32; off; off >>= 1) ss += __shfl_xor(ss, off, 64);
    const float r = rsqrtf(ss * (1.0f / HD) + EPSF);
    x0 = x0 * r * w[lane];
    x1 = x1 * r * w[lane + 64];

    const float inv_freq = expf(-(float)lane * (logf(10000.0f) / 64.0f));
    const float ang = (float)s * inv_freq;
    const float c = cosf(ang);
    const float sn = sinf(ang);
    base[lane]      = f2bf(x0 * c - x1 * sn);
    base[lane + 64] = f2bf(x1 * c + x0 * sn);
}

// ---------------------------------------------------------------------------
// Transpose V (bf16): qkv[token][2560 + kvh*128 + d] -> vT[b][kvh][d][s]
// ---------------------------------------------------------------------------
__global__ __launch_bounds__(256)
void transpose_v(const short* __restrict__ qkv, short* __restrict__ vT)
{
    __shared__ short T[32][33];
    const int bx = blockIdx.x;
    const int st = bx & 63;
    const int dt = (bx >> 6) & 3;
    const int bk = bx >> 8;
    const int s0 = st * 32, d0 = dt * 32;
    const int tid = threadIdx.x;
    const long tok0 = (long)(bk >> 2) * SEQ + s0;
    const int kvh = bk & 3;

    const int rs = tid >> 3;
    const int rc = (tid & 7) * 4;
    short4v val = *(const short4v*)(qkv + (tok0 + rs) * QKV + 2560 + kvh * HD + d0 + rc);
    T[rc + 0][rs] = val.x; T[rc + 1][rs] = val.y;
    T[rc + 2][rs] = val.z; T[rc + 3][rs] = val.w;
    __syncthreads();

    const int wd = tid >> 3;
    const int wsc = (tid & 7) * 4;
    short4v ov;
    ov.x = T[wd][wsc + 0]; ov.y = T[wd][wsc + 1];
    ov.z = T[wd][wsc + 2]; ov.w = T[wd][wsc + 3];
    *(short4v*)(vT + ((size_t)bk * HD + d0 + wd) * SEQ + s0 + wsc) = ov;
}

// ---------------------------------------------------------------------------
// Flash causal GQA attention v3, bf16 MFMA, fp32 accum.
// 512 threads = 8 waves, side-split: waves 0-3 process q-tile qa, waves 4-7
// process qb (pair qa+qb=31 -> every block = 33 subtile-units). Both sides
// share each staged 64-key K/V tile. Register prefetch pipelines the next
// tile's global loads under compute. Scores = K@Q^T (per-lane softmax state),
// PV as O^T = V^T @ P^T. Grid = 16 pairs x 32 (b,h) = 512 blocks.
// ---------------------------------------------------------------------------
__global__ __launch_bounds__(512, 4)
void flash_attn_mfma(const short* __restrict__ qkv, const short* __restrict__ vT,
                     short* __restrict__ o)
{
    __shared__ short Ks[64][144];      // [key][d]   288B rows
    __shared__ short Vt[128][80];      // [d][key]   160B rows
    __shared__ short Ps[8][16][80];    // per-wave [q][key]

    const int tid = threadIdx.x;
    const int w = tid >> 6;            // 0..7
    const int lane = tid & 63;
    const int quad = lane >> 4;
    const int ln = lane & 15;
    const int side = w >> 2;           // 0 -> qa, 1 -> qb
    const int sw = w & 3;

    const int bx = blockIdx.x;
    const int pair = bx & 15;
    const int bh = bx >> 4;
    const int h = bh & 15;
    const int b = bh >> 4;
    const int kvh = h >> 2;
    const int qa = pair, qb = 31 - pair;
    const int qX = side ? qb : qa;
    const int rX = qX * 64 + sw * 16;

    const float SC = 0.08838834764831845f * 1.4426950408889634f; // 1/sqrt(HD)*log2e

    // Q -> B-frags (lane ln = q row rX+ln)
    bf16x8 qf[4];
    {
        const short* qrow = qkv + (size_t)(b * SEQ + rX + ln) * QKV + h * HD;
        #pragma unroll
        for (int f = 0; f < 4; ++f)
            qf[f] = *(const bf16x8*)(qrow + f * 32 + quad * 8);
    }

    f32x4 Oa[8];
    #pragma unroll
    for (int dg = 0; dg < 8; ++dg) Oa[dg] = (f32x4){0.f, 0.f, 0.f, 0.f};
    float mX = -1e30f, lX = 0.f;

    const short* kbase = qkv + (size_t)(b * SEQ) * QKV + 2048 + kvh * HD;
    const short* vbase = vT + (size_t)(b * NKV + kvh) * HD * SEQ;

    // register prefetch: K tile 64x128 = 1024 bf16x8 units, V^T 128x64 = 1024
    bf16x8 kp[2], vp[2];
    auto prefetch = [&](int k0) {
        #pragma unroll
        for (int i = 0; i < 2; ++i) {
            const int e = tid + i * 512;
            kp[i] = *(const bf16x8*)(kbase + (size_t)(k0 + (e >> 4)) * QKV + (e & 15) * 8);
            vp[i] = *(const bf16x8*)(vbase + (size_t)(e >> 3) * SEQ + k0 + (e & 7) * 8);
        }
    };
    prefetch(0);

    for (int kt = 0; kt <= qb; ++kt) {
        const int k0 = kt * 64;
        __syncthreads();                       // prev tile's consumers done
        #pragma unroll
        for (int i = 0; i < 2; ++i) {
            const int e = tid + i * 512;
            *(bf16x8*)&Ks[e >> 4][(e & 15) * 8] = kp[i];
            *(bf16x8*)&Vt[e >> 3][(e & 7) * 8] = vp[i];
        }
        __syncthreads();                       // tile staged
        if (kt < qb) prefetch(k0 + 64);        // overlap next loads w/ compute

        if (kt <= qX) {
            // K@Q^T: D[key = quad*4+reg (+16g)][q = ln]
            f32x4 s[4];
            #pragma unroll
            for (int g = 0; g < 4; ++g) {
                f32x4 acc = (f32x4){0.f, 0.f, 0.f, 0.f};
                #pragma unroll
                for (int f = 0; f < 4; ++f) {
                    bf16x8 kf = *(const bf16x8*)&Ks[g * 16 + ln][f * 32 + quad * 8];
                    acc = __builtin_amdgcn_mfma_f32_16x16x32_bf16(kf, qf[f], acc, 0, 0, 0);
                }
                s[g] = acc;
            }
            // causal mask: only the diagonal tile (kt == qX)
            if (kt == qX) {
                const int qrow = rX + ln;
                #pragma unroll
                for (int g = 0; g < 4; ++g)
                    #pragma unroll
                    for (int reg = 0; reg < 4; ++reg) {
                        const int key = k0 + g * 16 + quad * 4 + reg;
                        if (key > qrow) s[g][reg] = -1e30f;
                    }
            }
            // per-lane online softmax (16 scores/lane); cross-quad combine
            float mt = s[0][0];
            #pragma unroll
            for (int g = 0; g < 4; ++g)
                #pragma unroll
                for (int reg = 0; reg < 4; ++reg)
                    mt = fmaxf(mt, s[g][reg]);
            mt = fmaxf(mt, __shfl_xor(mt, 16, 64));
            mt = fmaxf(mt, __shfl_xor(mt, 32, 64));
            const float mnew = fmaxf(mX, mt);
            const float c1 = SC * mnew;
            const float alpha = exp2f(__builtin_fmaf(SC, mX, -c1));
            float ps = 0.f;
            #pragma unroll
            for (int g = 0; g < 4; ++g) {
                float p0 = exp2f(__builtin_fmaf(s[g][0], SC, -c1));
                float p1 = exp2f(__builtin_fmaf(s[g][1], SC, -c1));
                float p2 = exp2f(__builtin_fmaf(s[g][2], SC, -c1));
                float p3 = exp2f(__builtin_fmaf(s[g][3], SC, -c1));
                ps += (p0 + p1) + (p2 + p3);
                uint2 pk;                       // v_cvt_pk_bf16_f32 x2
                pk.x = pkbf(p0, p1);
                pk.y = pkbf(p2, p3);
                *(uint2*)&Ps[w][ln][g * 16 + quad * 4] = pk;
            }
            ps += __shfl_xor(ps, 16, 64);
            ps += __shfl_xor(ps, 32, 64);
            lX = lX * alpha + ps;
            mX = mnew;
            #pragma unroll
            for (int dg = 0; dg < 8; ++dg) {
                Oa[dg][0] *= alpha; Oa[dg][1] *= alpha;
                Oa[dg][2] *= alpha; Oa[dg][3] *= alpha;
            }
            __asm volatile("s_waitcnt lgkmcnt(0)" ::: "memory");
            // O^T = V^T @ P^T: D[d = quad*4+reg (+16dg)][q = ln]
            bf16x8 pf0 = *(const bf16x8*)&Ps[w][ln][quad * 8];
            bf16x8 pf1 = *(const bf16x8*)&Ps[w][ln][32 + quad * 8];
            #pragma unroll
            for (int dg = 0; dg < 8; ++dg) {
                bf16x8 vf0 = *(const bf16x8*)&Vt[dg * 16 + ln][quad * 8];
                bf16x8 vf1 = *(const bf16x8*)&Vt[dg * 16 + ln][32 + quad * 8];
                Oa[dg] = __builtin_amdgcn_mfma_f32_16x16x32_bf16(vf0, pf0, Oa[dg], 0, 0, 0);
                Oa[dg] = __builtin_amdgcn_mfma_f32_16x16x32_bf16(vf1, pf1, Oa[dg], 0, 0, 0);
            }
        }
    }

    // epilogue: lane owns q-row rX+ln; d = dg*16 + quad*4 + {0..3}
    {
        const float inv = 1.0f / lX;
        short* orow = o + ((size_t)(b * SEQ + rX + ln) * NH + h) * HD;
        #pragma unroll
        for (int dg = 0; dg < 8; ++dg) {
            uint2 ov;
            ov.x = pkbf(Oa[dg][0] * inv, Oa[dg][1] * inv);
            ov.y = pkbf(Oa[dg][2] * inv, Oa[dg][3] * inv);
            *(uint2*)(orow + dg * 16 + quad * 4) = ov;
        }
    }
}

// ---------------------------------------------------------------------------
extern "C" void kernel_launch(void* const* d_in, const int* in_sizes, int n_in,
                              void* d_out, int out_size, void* d_ws, size_t ws_size,
                              hipStream_t stream)
{
    const float* hs = (const float*)d_in[0];
    const float* Wq = (const float*)d_in[2];
    const float* Wk = (const float*)d_in[3];
    const float* Wv = (const float*)d_in[4];
    const float* Wo = (const float*)d_in[5];
    const float* qw = (const float*)d_in[6];
    const float* kw = (const float*)d_in[7];
    float* out = (float*)d_out;

    const size_t MEG = 1024 * 1024;
    short* hsb  = (short*)d_ws;          // 8M bf16: hs; later reused as attn-out
    short* wqkv = hsb + 8 * MEG;         // 6M bf16: Wq|Wk|Wv fused [3072][2048]
    short* wob  = wqkv + 6 * MEG;        // 4M bf16: Wo
    short* qkvb = wob + 4 * MEG;         // 12M bf16: fused qkv [4096][3072]
    short* vT   = (short*)d_out;         // 4M bf16 in d_out (dead until O-proj)

    const int M = BATCH * SEQ;           // 4096
    dim3 blk(256);

    cast_all<<<dim3(18432), blk, 0, stream>>>(hs, Wq, Wk, Wv, Wo, hsb, wqkv, wob);

    gemm_nt_mfma<true><<<dim3(QKV / 128, M / 128), blk, 0, stream>>>(
        hsb, wqkv, qkvb, M, QKV, 2048);

    norm_rope_bf16<<<dim3((BATCH * SEQ * (NH + NKV)) / 4), blk, 0, stream>>>(
        qkvb, qw, kw);

    transpose_v<<<dim3(2048), blk, 0, stream>>>(qkvb, vT);

    flash_attn_mfma<<<dim3(512), dim3(512), 0, stream>>>(qkvb, vT, hsb);

    gemm_nt_mfma<false><<<dim3(2048 / 128, M / 128), blk, 0, stream>>>(
        hsb, wob, out, M, 2048, 2048);
}

// Round 7
// 330.014 us; speedup vs baseline: 10.9409x; 1.0860x over previous
//
#include <hip/hip_runtime.h>
#include <hip/hip_bf16.h>
#include <math.h>

#define NH 16
#define NKV 4
#define HD 128
#define SEQ 2048
#define BATCH 2
#define EPSF 1e-6f
#define QKV 3072      // fused projection width: 2048 q | 512 k | 512 v

typedef __attribute__((ext_vector_type(8))) short bf16x8;
typedef __attribute__((ext_vector_type(4))) short short4v;
typedef __attribute__((ext_vector_type(4))) float f32x4;

__device__ __forceinline__ short f2bf(float x) {
    unsigned u = __float_as_uint(x);
    u += 0x7fffu + ((u >> 16) & 1u);      // round-to-nearest-even
    return (short)(u >> 16);
}
__device__ __forceinline__ float bf2f(short x) {
    return __uint_as_float((unsigned)(unsigned short)x << 16);
}
// packed f32x2 -> bf16x2 (v_cvt_pk_bf16_f32), RNE
__device__ __forceinline__ unsigned pkbf(float a, float b) {
    __hip_bfloat162 h = __float22bfloat162_rn(float2{a, b});
    unsigned r; __builtin_memcpy(&r, &h, 4); return r;
}

// async global->LDS, 16B per lane; LDS dest = wave-uniform base + lane*16
__device__ __forceinline__ void gll16(const short* g, short* l) {
    __builtin_amdgcn_global_load_lds(
        (const __attribute__((address_space(1))) unsigned*)g,
        (__attribute__((address_space(3))) unsigned*)l, 16, 0, 0);
}

// ---------------------------------------------------------------------------
// Fused fp32->bf16 casts: hs(8M)->hsb, Wq(4M)|Wk(1M)|Wv(1M)->wqkv, Wo(4M)->wob
// ---------------------------------------------------------------------------
__global__ __launch_bounds__(256)
void cast_all(const float* __restrict__ hs, const float* __restrict__ Wq,
              const float* __restrict__ Wk, const float* __restrict__ Wv,
              const float* __restrict__ Wo, short* __restrict__ hsb,
              short* __restrict__ wqkv, short* __restrict__ wob)
{
    const size_t MEG = 1024 * 1024;
    const int id = blockIdx.x;
    const float* s;
    short* d;
    size_t off;
    if (id < 8192)       { s = hs; d = hsb;            off = (size_t)id * 1024; }
    else if (id < 12288) { s = Wq; d = wqkv;           off = (size_t)(id - 8192) * 1024; }
    else if (id < 13312) { s = Wk; d = wqkv + 4 * MEG; off = (size_t)(id - 12288) * 1024; }
    else if (id < 14336) { s = Wv; d = wqkv + 5 * MEG; off = (size_t)(id - 13312) * 1024; }
    else                 { s = Wo; d = wob;            off = (size_t)(id - 14336) * 1024; }
    const size_t i = off + threadIdx.x * 4;
    float4 v = *(const float4*)(s + i);
    short4v o;
    o.x = f2bf(v.x); o.y = f2bf(v.y); o.z = f2bf(v.z); o.w = f2bf(v.w);
    *(short4v*)(d + i) = o;
}

// ---------------------------------------------------------------------------
// bf16 MFMA GEMM NT v2: C[M,N] = A[M,K] @ B[N,K]^T, fp32 accum.
// 128x128 tile, BK=64, XOR-swizzled LDS (conflict-free, gll16-compatible),
// XCD-aware block remap. Grid = 1D (total blocks), 256 threads.
// Swizzle: logical 16B-granule gl of row R stored at physical gl ^ (R&7);
// staging achieves this by having lane (row'=l>>3, g=l&7) FETCH global
// granule g ^ row' while gll16 writes lane l at base + l*16.
// ---------------------------------------------------------------------------
template<bool OUT_BF16>
__global__ __launch_bounds__(256, 3)
void gemm_nt_mfma(const short* __restrict__ A, const short* __restrict__ B,
                  void* __restrict__ Cv, int N, int K, int gridX, int total)
{
    __shared__ short As[128 * 64];
    __shared__ short Bs[128 * 64];

    const int tid = threadIdx.x;
    const int w = tid >> 6, lane = tid & 63;
    const int quad = lane >> 4, ln = lane & 15;
    const int mw = (w >> 1) * 64, nw = (w & 1) * 64;

    // XCD-aware remap: XCD (id&7) walks a contiguous chunk of tiles
    const int id = blockIdx.x;
    const int t = (id & 7) * (total >> 3) + (id >> 3);
    const int n0 = (t % gridX) * 128;
    const int m0 = (t / gridX) * 128;

    // staging: wave w, round r covers rows w*8 + 32r + (lane>>3),
    // lane fetches swizzled source granule ((lane&7) ^ (lane>>3))
    const int rr = lane >> 3;
    const int gsw = ((lane & 7) ^ rr) * 8;
    const short* Ag[4]; const short* Bg[4];
    short* Al[4]; short* Bl[4];
    #pragma unroll
    for (int r = 0; r < 4; ++r) {
        const int row = w * 8 + 32 * r + rr;
        Ag[r] = A + (size_t)(m0 + row) * K + gsw;
        Bg[r] = B + (size_t)(n0 + row) * K + gsw;
        Al[r] = &As[(w * 8 + 32 * r) * 64];
        Bl[r] = &Bs[(w * 8 + 32 * r) * 64];
    }

    // read column offsets (shorts) for substeps ks=0,1: ((ks*4+quad)^(ln&7))*8
    const int col0 = ((quad) ^ (ln & 7)) * 8;
    const int col1 = ((4 + quad) ^ (ln & 7)) * 8;

    f32x4 acc[4][4];
    #pragma unroll
    for (int i = 0; i < 4; ++i)
        #pragma unroll
        for (int j = 0; j < 4; ++j)
            acc[i][j] = (f32x4){0.f, 0.f, 0.f, 0.f};

    for (int k0 = 0; k0 < K; k0 += 64) {
        __syncthreads();
        #pragma unroll
        for (int r = 0; r < 4; ++r) {
            gll16(Ag[r] + k0, Al[r]);
            gll16(Bg[r] + k0, Bl[r]);
        }
        __syncthreads();   // drains vmcnt -> LDS populated

        #pragma unroll
        for (int ks = 0; ks < 2; ++ks) {
            const int col = ks ? col1 : col0;
            bf16x8 af[4], bfr[4];
            #pragma unroll
            for (int i = 0; i < 4; ++i)
                af[i] = *(const bf16x8*)&As[(mw + i * 16 + ln) * 64 + col];
            #pragma unroll
            for (int j = 0; j < 4; ++j)
                bfr[j] = *(const bf16x8*)&Bs[(nw + j * 16 + ln) * 64 + col];
            #pragma unroll
            for (int i = 0; i < 4; ++i)
                #pragma unroll
                for (int j = 0; j < 4; ++j)
                    acc[i][j] = __builtin_amdgcn_mfma_f32_16x16x32_bf16(
                        af[i], bfr[j], acc[i][j], 0, 0, 0);
        }
    }

    #pragma unroll
    for (int i = 0; i < 4; ++i) {
        #pragma unroll
        for (int reg = 0; reg < 4; ++reg) {
            const int row = m0 + mw + i * 16 + quad * 4 + reg;
            const size_t base = (size_t)row * N + n0 + nw;
            #pragma unroll
            for (int j = 0; j < 4; ++j) {
                if (OUT_BF16)
                    ((short*)Cv)[base + j * 16 + ln] = f2bf(acc[i][j][reg]);
                else
                    ((float*)Cv)[base + j * 16 + ln] = acc[i][j][reg];
            }
        }
    }
}

// ---------------------------------------------------------------------------
// Fused RMSNorm + RoPE on bf16 qkv[token][3072], in place (fp32 math).
// ---------------------------------------------------------------------------
__global__ __launch_bounds__(256)
void norm_rope_bf16(short* __restrict__ qkv, const float* __restrict__ qw,
                    const float* __restrict__ kw)
{
    const int wave = threadIdx.x >> 6;
    const int lane = threadIdx.x & 63;
    const long vec = (long)blockIdx.x * 4 + wave;
    const long NQ = (long)BATCH * SEQ * NH;

    short* base;
    const float* w;
    int s;
    if (vec < NQ) {
        const long token = vec / NH;
        const int h = (int)(vec % NH);
        s = (int)(token % SEQ);
        base = qkv + token * QKV + h * HD;
        w = qw;
    } else {
        const long t = vec - NQ;
        const long token = t / NKV;
        const int kvh = (int)(t % NKV);
        s = (int)(token % SEQ);
        base = qkv + token * QKV + 2048 + kvh * HD;
        w = kw;
    }

    float x0 = bf2f(base[lane]);
    float x1 = bf2f(base[lane + 64]);
    float ss = x0 * x0 + x1 * x1;
    #pragma unroll
    for (int off = 32; off; off >>= 1) ss += __shfl_xor(ss, off, 64);
    const float r = rsqrtf(ss * (1.0f / HD) + EPSF);
    x0 = x0 * r * w[lane];
    x1 = x1 * r * w[lane + 64];

    const float inv_freq = expf(-(float)lane * (logf(10000.0f) / 64.0f));
    const float ang = (float)s * inv_freq;
    const float c = cosf(ang);
    const float sn = sinf(ang);
    base[lane]      = f2bf(x0 * c - x1 * sn);
    base[lane + 64] = f2bf(x1 * c + x0 * sn);
}

// ---------------------------------------------------------------------------
// Transpose V (bf16): qkv[token][2560 + kvh*128 + d] -> vT[b][kvh][d][s]
// ---------------------------------------------------------------------------
__global__ __launch_bounds__(256)
void transpose_v(const short* __restrict__ qkv, short* __restrict__ vT)
{
    __shared__ short T[32][33];
    const int bx = blockIdx.x;
    const int st = bx & 63;
    const int dt = (bx >> 6) & 3;
    const int bk = bx >> 8;
    const int s0 = st * 32, d0 = dt * 32;
    const int tid = threadIdx.x;
    const long tok0 = (long)(bk >> 2) * SEQ + s0;
    const int kvh = bk & 3;

    const int rs = tid >> 3;
    const int rc = (tid & 7) * 4;
    short4v val = *(const short4v*)(qkv + (tok0 + rs) * QKV + 2560 + kvh * HD + d0 + rc);
    T[rc + 0][rs] = val.x; T[rc + 1][rs] = val.y;
    T[rc + 2][rs] = val.z; T[rc + 3][rs] = val.w;
    __syncthreads();

    const int wd = tid >> 3;
    const int wsc = (tid & 7) * 4;
    short4v ov;
    ov.x = T[wd][wsc + 0]; ov.y = T[wd][wsc + 1];
    ov.z = T[wd][wsc + 2]; ov.w = T[wd][wsc + 3];
    *(short4v*)(vT + ((size_t)bk * HD + d0 + wd) * SEQ + s0 + wsc) = ov;
}

// ---------------------------------------------------------------------------
// Flash causal GQA attention v3 (unchanged from R6), bf16 MFMA, fp32 accum.
// ---------------------------------------------------------------------------
__global__ __launch_bounds__(512, 4)
void flash_attn_mfma(const short* __restrict__ qkv, const short* __restrict__ vT,
                     short* __restrict__ o)
{
    __shared__ short Ks[64][144];      // [key][d]   288B rows
    __shared__ short Vt[128][80];      // [d][key]   160B rows
    __shared__ short Ps[8][16][80];    // per-wave [q][key]

    const int tid = threadIdx.x;
    const int w = tid >> 6;            // 0..7
    const int lane = tid & 63;
    const int quad = lane >> 4;
    const int ln = lane & 15;
    const int side = w >> 2;           // 0 -> qa, 1 -> qb
    const int sw = w & 3;

    const int bx = blockIdx.x;
    const int pair = bx & 15;
    const int bh = bx >> 4;
    const int h = bh & 15;
    const int b = bh >> 4;
    const int kvh = h >> 2;
    const int qa = pair, qb = 31 - pair;
    const int qX = side ? qb : qa;
    const int rX = qX * 64 + sw * 16;

    const float SC = 0.08838834764831845f * 1.4426950408889634f; // 1/sqrt(HD)*log2e

    // Q -> B-frags (lane ln = q row rX+ln)
    bf16x8 qf[4];
    {
        const short* qrow = qkv + (size_t)(b * SEQ + rX + ln) * QKV + h * HD;
        #pragma unroll
        for (int f = 0; f < 4; ++f)
            qf[f] = *(const bf16x8*)(qrow + f * 32 + quad * 8);
    }

    f32x4 Oa[8];
    #pragma unroll
    for (int dg = 0; dg < 8; ++dg) Oa[dg] = (f32x4){0.f, 0.f, 0.f, 0.f};
    float mX = -1e30f, lX = 0.f;

    const short* kbase = qkv + (size_t)(b * SEQ) * QKV + 2048 + kvh * HD;
    const short* vbase = vT + (size_t)(b * NKV + kvh) * HD * SEQ;

    bf16x8 kp[2], vp[2];
    auto prefetch = [&](int k0) {
        #pragma unroll
        for (int i = 0; i < 2; ++i) {
            const int e = tid + i * 512;
            kp[i] = *(const bf16x8*)(kbase + (size_t)(k0 + (e >> 4)) * QKV + (e & 15) * 8);
            vp[i] = *(const bf16x8*)(vbase + (size_t)(e >> 3) * SEQ + k0 + (e & 7) * 8);
        }
    };
    prefetch(0);

    for (int kt = 0; kt <= qb; ++kt) {
        const int k0 = kt * 64;
        __syncthreads();
        #pragma unroll
        for (int i = 0; i < 2; ++i) {
            const int e = tid + i * 512;
            *(bf16x8*)&Ks[e >> 4][(e & 15) * 8] = kp[i];
            *(bf16x8*)&Vt[e >> 3][(e & 7) * 8] = vp[i];
        }
        __syncthreads();
        if (kt < qb) prefetch(k0 + 64);

        if (kt <= qX) {
            f32x4 s[4];
            #pragma unroll
            for (int g = 0; g < 4; ++g) {
                f32x4 acc = (f32x4){0.f, 0.f, 0.f, 0.f};
                #pragma unroll
                for (int f = 0; f < 4; ++f) {
                    bf16x8 kf = *(const bf16x8*)&Ks[g * 16 + ln][f * 32 + quad * 8];
                    acc = __builtin_amdgcn_mfma_f32_16x16x32_bf16(kf, qf[f], acc, 0, 0, 0);
                }
                s[g] = acc;
            }
            if (kt == qX) {
                const int qrow = rX + ln;
                #pragma unroll
                for (int g = 0; g < 4; ++g)
                    #pragma unroll
                    for (int reg = 0; reg < 4; ++reg) {
                        const int key = k0 + g * 16 + quad * 4 + reg;
                        if (key > qrow) s[g][reg] = -1e30f;
                    }
            }
            float mt = s[0][0];
            #pragma unroll
            for (int g = 0; g < 4; ++g)
                #pragma unroll
                for (int reg = 0; reg < 4; ++reg)
                    mt = fmaxf(mt, s[g][reg]);
            mt = fmaxf(mt, __shfl_xor(mt, 16, 64));
            mt = fmaxf(mt, __shfl_xor(mt, 32, 64));
            const float mnew = fmaxf(mX, mt);
            const float c1 = SC * mnew;
            const float alpha = exp2f(__builtin_fmaf(SC, mX, -c1));
            float ps = 0.f;
            #pragma unroll
            for (int g = 0; g < 4; ++g) {
                float p0 = exp2f(__builtin_fmaf(s[g][0], SC, -c1));
                float p1 = exp2f(__builtin_fmaf(s[g][1], SC, -c1));
                float p2 = exp2f(__builtin_fmaf(s[g][2], SC, -c1));
                float p3 = exp2f(__builtin_fmaf(s[g][3], SC, -c1));
                ps += (p0 + p1) + (p2 + p3);
                uint2 pk;
                pk.x = pkbf(p0, p1);
                pk.y = pkbf(p2, p3);
                *(uint2*)&Ps[w][ln][g * 16 + quad * 4] = pk;
            }
            ps += __shfl_xor(ps, 16, 64);
            ps += __shfl_xor(ps, 32, 64);
            lX = lX * alpha + ps;
            mX = mnew;
            #pragma unroll
            for (int dg = 0; dg < 8; ++dg) {
                Oa[dg][0] *= alpha; Oa[dg][1] *= alpha;
                Oa[dg][2] *= alpha; Oa[dg][3] *= alpha;
            }
            __asm volatile("s_waitcnt lgkmcnt(0)" ::: "memory");
            bf16x8 pf0 = *(const bf16x8*)&Ps[w][ln][quad * 8];
            bf16x8 pf1 = *(const bf16x8*)&Ps[w][ln][32 + quad * 8];
            #pragma unroll
            for (int dg = 0; dg < 8; ++dg) {
                bf16x8 vf0 = *(const bf16x8*)&Vt[dg * 16 + ln][quad * 8];
                bf16x8 vf1 = *(const bf16x8*)&Vt[dg * 16 + ln][32 + quad * 8];
                Oa[dg] = __builtin_amdgcn_mfma_f32_16x16x32_bf16(vf0, pf0, Oa[dg], 0, 0, 0);
                Oa[dg] = __builtin_amdgcn_mfma_f32_16x16x32_bf16(vf1, pf1, Oa[dg], 0, 0, 0);
            }
        }
    }

    {
        const float inv = 1.0f / lX;
        short* orow = o + ((size_t)(b * SEQ + rX + ln) * NH + h) * HD;
        #pragma unroll
        for (int dg = 0; dg < 8; ++dg) {
            uint2 ov;
            ov.x = pkbf(Oa[dg][0] * inv, Oa[dg][1] * inv);
            ov.y = pkbf(Oa[dg][2] * inv, Oa[dg][3] * inv);
            *(uint2*)(orow + dg * 16 + quad * 4) = ov;
        }
    }
}

// ---------------------------------------------------------------------------
extern "C" void kernel_launch(void* const* d_in, const int* in_sizes, int n_in,
                              void* d_out, int out_size, void* d_ws, size_t ws_size,
                              hipStream_t stream)
{
    const float* hs = (const float*)d_in[0];
    const float* Wq = (const float*)d_in[2];
    const float* Wk = (const float*)d_in[3];
    const float* Wv = (const float*)d_in[4];
    const float* Wo = (const float*)d_in[5];
    const float* qw = (const float*)d_in[6];
    const float* kw = (const float*)d_in[7];
    float* out = (float*)d_out;

    const size_t MEG = 1024 * 1024;
    short* hsb  = (short*)d_ws;          // 8M bf16: hs; later reused as attn-out
    short* wqkv = hsb + 8 * MEG;         // 6M bf16: Wq|Wk|Wv fused [3072][2048]
    short* wob  = wqkv + 6 * MEG;        // 4M bf16: Wo
    short* qkvb = wob + 4 * MEG;         // 12M bf16: fused qkv [4096][3072]
    short* vT   = (short*)d_out;         // 4M bf16 in d_out (dead until O-proj)

    dim3 blk(256);

    cast_all<<<dim3(18432), blk, 0, stream>>>(hs, Wq, Wk, Wv, Wo, hsb, wqkv, wob);

    // fused QKV projection: grid 768 blocks (24 n-tiles x 32 m-tiles)
    gemm_nt_mfma<true><<<dim3(768), blk, 0, stream>>>(
        hsb, wqkv, qkvb, QKV, 2048, 24, 768);

    norm_rope_bf16<<<dim3((BATCH * SEQ * (NH + NKV)) / 4), blk, 0, stream>>>(
        qkvb, qw, kw);

    transpose_v<<<dim3(2048), blk, 0, stream>>>(qkvb, vT);

    flash_attn_mfma<<<dim3(512), dim3(512), 0, stream>>>(qkvb, vT, hsb);

    // output projection: grid 512 blocks (16 n-tiles x 32 m-tiles)
    gemm_nt_mfma<false><<<dim3(512), blk, 0, stream>>>(
        hsb, wob, out, 2048, 2048, 16, 512);
}